// Round 6
// baseline (172.046 us; speedup 1.0000x reference)
//
#include <hip/hip_runtime.h>
#include <hip/hip_bf16.h>
#include <math.h>

#define DIM 192
#define NHD 6
#define HD 32
#define KSZ 7
#define HID 768
#define IMH 128
#define IMW 128
#define NPIX (IMH*IMW)
#define WIN 14
#define KPAD 40

typedef __attribute__((ext_vector_type(8))) short short8;
typedef __attribute__((ext_vector_type(4))) float f32x4;

#define LDS_SYNC() do { \
    asm volatile("s_waitcnt lgkmcnt(0)" ::: "memory"); \
    __builtin_amdgcn_sched_barrier(0); \
    __builtin_amdgcn_s_barrier(); } while (0)

__device__ __forceinline__ void gl_lds16(const void* g, void* l) {
    __builtin_amdgcn_global_load_lds(
        (const __attribute__((address_space(1))) void*)g,
        (__attribute__((address_space(3))) void*)l, 16, 0, 0);
}

__device__ __forceinline__ short8 cvt8(float4 a, float4 b) {
    union { short8 v; __hip_bfloat16 h[8]; } u;
    u.h[0] = __float2bfloat16(a.x); u.h[1] = __float2bfloat16(a.y);
    u.h[2] = __float2bfloat16(a.z); u.h[3] = __float2bfloat16(a.w);
    u.h[4] = __float2bfloat16(b.x); u.h[5] = __float2bfloat16(b.y);
    u.h[6] = __float2bfloat16(b.z); u.h[7] = __float2bfloat16(b.w);
    return u.v;
}

// ---- 1024-thread staging: 64 rows x 192 K (1536 slots of 16B), 96 slots/wave,
// exactly 2 VMEM issues per wave (2nd exec-masked to 32 lanes) -> uniform vmcnt.
__device__ __forceinline__ void stage_rows(const __hip_bfloat16* __restrict__ src,
                                           char* ldsbase, int wave, int lane) {
    int c0 = wave * 96 + lane;
    int r0 = c0 / 24, k0 = c0 - r0 * 24;
    gl_lds16(src + (size_t)r0 * DIM + ((k0 ^ (r0 & 7)) * 8), ldsbase + (wave * 96) * 16);
    int c1 = wave * 96 + 64 + (lane & 31);
    int r1 = c1 / 24, k1 = c1 - r1 * 24;
    if (lane < 32)
        gl_lds16(src + (size_t)r1 * DIM + ((k1 ^ (r1 & 7)) * 8), ldsbase + (wave * 96 + 64) * 16);
}
// ---- FC2 weight chunk: 192 n-rows x 64 K (8 slots/row), same 96-slot/wave split
__device__ __forceinline__ void stage_w2(const __hip_bfloat16* __restrict__ W2, int ch,
                                         char* ldsbase, int wave, int lane) {
    int i0 = wave * 96 + lane;
    int r0 = i0 >> 3, o0 = i0 & 7;
    gl_lds16(W2 + (size_t)r0 * HID + ch * 64 + ((o0 ^ (r0 & 7)) * 8), ldsbase + (wave * 96) * 16);
    int i1 = wave * 96 + 64 + (lane & 31);
    int r1 = i1 >> 3, o1 = i1 & 7;
    if (lane < 32)
        gl_lds16(W2 + (size_t)r1 * HID + ch * 64 + ((o1 ^ (r1 & 7)) * 8), ldsbase + (wave * 96 + 64) * 16);
}

// ---------------- QKV GEMM with fused LN1 + inline wq fp32->bf16 (T14 reg-staged) ----------------
// blocks 0..511: 32 rows x full 576 cols. blocks 512..835: piggyback cvt of wp/wf1/wf2
// (consumed only by tail_fused, two kernels later -> safe ordering).
__global__ __launch_bounds__(256, 2) void qkv_ln_gemm(
    const float* __restrict__ x, const float* __restrict__ lnw, const float* __restrict__ lnb,
    const float* __restrict__ Wf, const float* __restrict__ bias,
    float* __restrict__ qb, __hip_bfloat16* __restrict__ kb, __hip_bfloat16* __restrict__ vb,
    const float* __restrict__ pw, const float* __restrict__ f1w, const float* __restrict__ f2w,
    __hip_bfloat16* __restrict__ dp, __hip_bfloat16* __restrict__ df1, __hip_bfloat16* __restrict__ df2)
{
    __shared__ __hip_bfloat16 As[32 * 192];      // 12 KB
    __shared__ __hip_bfloat16 Ws2[2][64 * 192];  // 2 x 24 KB

    if (blockIdx.x >= 512) {
        // piggyback: wp/wf1/wf2 fp32 -> bf16 (324 blocks x 1024 elems)
        int blk = blockIdx.x - 512, t = threadIdx.x;
        const float* s; __hip_bfloat16* d; int base;
        if (blk < 36)       { s = pw;  d = dp;  base = blk * 1024; }
        else if (blk < 180) { s = f1w; d = df1; base = (blk - 36) * 1024; }
        else                { s = f2w; d = df2; base = (blk - 180) * 1024; }
        int idx = base + t * 4;
        float4 v4 = *(const float4*)(s + idx);
        union { ushort4 u; __hip_bfloat16 h[4]; } o;
        o.h[0] = __float2bfloat16(v4.x); o.h[1] = __float2bfloat16(v4.y);
        o.h[2] = __float2bfloat16(v4.z); o.h[3] = __float2bfloat16(v4.w);
        *(ushort4*)&d[idx] = o.u;
        return;
    }

    int tid = threadIdx.x;
    int wave = tid >> 6, lane = tid & 63;
    int q = lane >> 4, col = lane & 15;
    int wm = (wave >> 1) * 16, wn = (wave & 1) * 32;
    int m0 = blockIdx.x * 32;

    // reg-staged weight pipeline: load fp32 (inverse-swizzled source) -> cvt -> LDS linear
    float4 wreg[12];
    auto loadW = [&](int ch) {
        #pragma unroll
        for (int i = 0; i < 6; i++) {
            int c = i * 256 + tid;
            int r = c / 24, kc = c - r * 24;
            const float* src = Wf + (size_t)(ch * 64 + r) * DIM + ((kc ^ (r & 7)) * 8);
            wreg[2 * i]     = *(const float4*)src;
            wreg[2 * i + 1] = *(const float4*)(src + 4);
        }
    };
    auto writeW = [&](int buf) {
        #pragma unroll
        for (int i = 0; i < 6; i++) {
            int c = i * 256 + tid;
            *(short8*)((char*)&Ws2[buf][0] + c * 16) = cvt8(wreg[2 * i], wreg[2 * i + 1]);
        }
    };

    loadW(0);   // chunk-0 fp32 loads fly under LN1 compute

    // ---- LN1: 8 lanes per row, 24 cols each ----
    {
        int row = tid >> 3, sub = tid & 7;
        const float4* xr = (const float4*)(x + (size_t)(m0 + row) * DIM + sub * 24);
        float4 xa[6];
        float s = 0.f;
        #pragma unroll
        for (int i = 0; i < 6; i++) {
            xa[i] = xr[i];
            s += xa[i].x + xa[i].y + xa[i].z + xa[i].w;
        }
        s += __shfl_xor(s, 1); s += __shfl_xor(s, 2); s += __shfl_xor(s, 4);
        float mu = s * (1.0f / DIM);
        float qs = 0.f;
        #pragma unroll
        for (int i = 0; i < 6; i++) {
            float a = xa[i].x - mu, b = xa[i].y - mu, c = xa[i].z - mu, d = xa[i].w - mu;
            qs += a * a + b * b + c * c + d * d;
        }
        qs += __shfl_xor(qs, 1); qs += __shfl_xor(qs, 2); qs += __shfl_xor(qs, 4);
        float rstd = rsqrtf(qs * (1.0f / DIM) + 1e-5f);
        const float4* wv = (const float4*)(lnw + sub * 24);
        const float4* bv = (const float4*)(lnb + sub * 24);
        #pragma unroll
        for (int j = 0; j < 3; j++) {
            float4 v0 = xa[j * 2], v1 = xa[j * 2 + 1];
            float4 w0 = wv[j * 2], w1 = wv[j * 2 + 1];
            float4 b0 = bv[j * 2], b1 = bv[j * 2 + 1];
            float4 o0, o1;
            o0.x = (v0.x - mu) * rstd * w0.x + b0.x;
            o0.y = (v0.y - mu) * rstd * w0.y + b0.y;
            o0.z = (v0.z - mu) * rstd * w0.z + b0.z;
            o0.w = (v0.w - mu) * rstd * w0.w + b0.w;
            o1.x = (v1.x - mu) * rstd * w1.x + b1.x;
            o1.y = (v1.y - mu) * rstd * w1.y + b1.y;
            o1.z = (v1.z - mu) * rstd * w1.z + b1.z;
            o1.w = (v1.w - mu) * rstd * w1.w + b1.w;
            int oct = sub * 3 + j;
            *(short8*)&As[row * 192 + ((oct ^ (row & 7)) * 8)] = cvt8(o0, o1);
        }
    }
    asm volatile("s_waitcnt vmcnt(0)" ::: "memory");   // wreg(chunk0) arrived
    writeW(0);
    asm volatile("s_waitcnt lgkmcnt(0)" ::: "memory"); // As + Ws writes done
    __builtin_amdgcn_sched_barrier(0);
    __builtin_amdgcn_s_barrier();

    short8 af[6];
    {
        int rA = wm + col;
        #pragma unroll
        for (int ks = 0; ks < 6; ks++)
            af[ks] = *(const short8*)&As[rA * 192 + (((ks * 4 + q) ^ (rA & 7)) * 8)];
    }

    for (int ch = 0; ch < 9; ch++) {
        if (ch < 8) loadW(ch + 1);   // issue early: latency hides under MFMA+epilogue
        const __hip_bfloat16* wsb = &Ws2[ch & 1][0];
        f32x4 acc[2] = {};
        #pragma unroll
        for (int ks = 0; ks < 6; ks++) {
            #pragma unroll
            for (int ni = 0; ni < 2; ni++) {
                int rB = wn + ni * 16 + col;
                short8 bf = *(const short8*)&wsb[rB * 192 + (((ks * 4 + q) ^ (rB & 7)) * 8)];
                acc[ni] = __builtin_amdgcn_mfma_f32_16x16x32_bf16(af[ks], bf, acc[ni], 0, 0, 0);
            }
        }
        if (ch < 8) {
            asm volatile("s_waitcnt vmcnt(0)" ::: "memory");  // wreg(ch+1) arrived
            writeW((ch + 1) & 1);
        }
        #pragma unroll
        for (int ni = 0; ni < 2; ni++) {
            int n = ch * 64 + wn + ni * 16 + col;
            float bi = bias[n];
            int h18 = n >> 5;
            int sel = h18 / 6;
            int head = h18 - sel * 6;
            #pragma unroll
            for (int r4 = 0; r4 < 4; r4++) {
                int m = m0 + wm + q * 4 + r4;
                float v = acc[ni][r4] + bi;
                size_t idx = ((size_t)head * NPIX + m) * 32 + (n & 31);
                if (sel == 0)      qb[idx] = v * 0.17677669529663687f;
                else if (sel == 1) kb[idx] = __float2bfloat16(v);
                else               vb[idx] = __float2bfloat16(v);
            }
        }
        if (ch < 8) {
            asm volatile("s_waitcnt lgkmcnt(0)" ::: "memory");
            __builtin_amdgcn_sched_barrier(0);
            __builtin_amdgcn_s_barrier();
        }
    }
}

// ---------------- fused tail, 16 waves (unchanged from round 4) ----------------
__global__ __launch_bounds__(1024, 4) void tail_fused(
    const __hip_bfloat16* __restrict__ A, const __hip_bfloat16* __restrict__ Wp,
    const float* __restrict__ pb, const float* __restrict__ resid,
    const float* __restrict__ gamma1, const float* __restrict__ ln2w, const float* __restrict__ ln2b,
    const __hip_bfloat16* __restrict__ W1, const float* __restrict__ b1,
    const __hip_bfloat16* __restrict__ W2, const float* __restrict__ b2,
    const float* __restrict__ gamma2, const int* __restrict__ quality,
    float* __restrict__ outf)
{
    __shared__ __hip_bfloat16 arena[64 * 768];     // 96 KB: Ms; top 24 KB doubles as Hs
    __shared__ __hip_bfloat16 Wsb[2][64 * 192];    // 2 x 24 KB
    __shared__ float lnred[4][64][2];              // 2 KB
    __hip_bfloat16* Hs = arena + 36864;            // 24 KB

    int tid = threadIdx.x;
    int wave = tid >> 6, lane = tid & 63;
    int q = lane >> 4, col = lane & 15;
    int wm = (wave >> 2) * 16, wq4 = wave & 3;
    int m0 = blockIdx.x * 64;
    int s = quality[0] - 1;

    stage_rows(A + (size_t)m0 * DIM, (char*)Hs, wave, lane);
    stage_rows(Wp, (char*)&Wsb[0][0], wave, lane);
    stage_rows(Wp + 64 * DIM, (char*)&Wsb[1][0], wave, lane);
    asm volatile("s_waitcnt vmcnt(2)" ::: "memory");
    __builtin_amdgcn_s_barrier();

    short8 afp[6];
    {
        int rA = wm + col;
        #pragma unroll
        for (int ks = 0; ks < 6; ks++)
            afp[ks] = *(const short8*)&Hs[rA * 192 + (((ks * 4 + q) ^ (rA & 7)) * 8)];
    }

    float v[3][4];
    float sm[4] = {}, sq[4] = {};
    auto proj_chunk = [&](int ch, const __hip_bfloat16* wsb) {
        f32x4 pacc = {};
        int rB = wq4 * 16 + col;
        #pragma unroll
        for (int ks = 0; ks < 6; ks++) {
            short8 bf = *(const short8*)&wsb[rB * 192 + (((ks * 4 + q) ^ (rB & 7)) * 8)];
            pacc = __builtin_amdgcn_mfma_f32_16x16x32_bf16(afp[ks], bf, pacc, 0, 0, 0);
        }
        int n = ch * 64 + wq4 * 16 + col;
        float bi = pb[n];
        float g = fabsf(gamma1[s * DIM + n]);
        #pragma unroll
        for (int r = 0; r < 4; r++) {
            int m = m0 + wm + q * 4 + r;
            v[ch][r] = resid[(size_t)m * DIM + n] + g * (pacc[r] + bi);
            sm[r] += v[ch][r]; sq[r] += v[ch][r] * v[ch][r];
        }
    };

    proj_chunk(0, &Wsb[0][0]);
    __builtin_amdgcn_s_barrier();
    stage_rows(Wp + 128 * DIM, (char*)&Wsb[0][0], wave, lane);
    asm volatile("s_waitcnt vmcnt(2)" ::: "memory");
    __builtin_amdgcn_s_barrier();
    proj_chunk(1, &Wsb[1][0]);
    __builtin_amdgcn_s_barrier();
    stage_rows(W1, (char*)&Wsb[1][0], wave, lane);
    asm volatile("s_waitcnt vmcnt(2)" ::: "memory");
    __builtin_amdgcn_s_barrier();
    proj_chunk(2, &Wsb[0][0]);

    #pragma unroll
    for (int off = 1; off <= 8; off <<= 1)
        #pragma unroll
        for (int r = 0; r < 4; r++) {
            sm[r] += __shfl_xor(sm[r], off);
            sq[r] += __shfl_xor(sq[r], off);
        }
    if (col == 0) {
        #pragma unroll
        for (int r = 0; r < 4; r++) {
            lnred[wq4][wm + q * 4 + r][0] = sm[r];
            lnred[wq4][wm + q * 4 + r][1] = sq[r];
        }
    }
    LDS_SYNC();
    float mu[4], rstd[4];
    #pragma unroll
    for (int r = 0; r < 4; r++) {
        int ml = wm + q * 4 + r;
        float smt = lnred[0][ml][0] + lnred[1][ml][0] + lnred[2][ml][0] + lnred[3][ml][0];
        float sqt = lnred[0][ml][1] + lnred[1][ml][1] + lnred[2][ml][1] + lnred[3][ml][1];
        mu[r] = smt * (1.0f / DIM);
        float var = sqt * (1.0f / DIM) - mu[r] * mu[r];
        rstd[r] = rsqrtf(var + 1e-5f);
    }
    #pragma unroll
    for (int ch = 0; ch < 3; ch++) {
        int n = ch * 64 + wq4 * 16 + col;
        float lw = ln2w[n], lb = ln2b[n];
        #pragma unroll
        for (int r = 0; r < 4; r++) {
            int ml = wm + q * 4 + r;
            Hs[ml * 192 + (((n >> 3) ^ (ml & 7)) * 8) + (n & 7)] =
                __float2bfloat16((v[ch][r] - mu[r]) * rstd[r] * lw + lb);
        }
    }
    LDS_SYNC();
    short8 af1[6];
    {
        int rowA = wm + col;
        #pragma unroll
        for (int ks = 0; ks < 6; ks++)
            af1[ks] = *(const short8*)&Hs[rowA * 192 + (((ks * 4 + q) ^ (rowA & 7)) * 8)];
    }
    LDS_SYNC();

    for (int t = 0; t < 12; t++) {
        if (t < 11) stage_rows(W1 + (size_t)(t + 1) * 64 * DIM, (char*)&Wsb[t & 1][0], wave, lane);
        else        stage_w2(W2, 0, (char*)&Wsb[1][0], wave, lane);
        asm volatile("s_waitcnt vmcnt(2)" ::: "memory");
        __builtin_amdgcn_s_barrier();
        const __hip_bfloat16* wsb = &Wsb[(t + 1) & 1][0];
        f32x4 a1 = {};
        int rB = wq4 * 16 + col;
        #pragma unroll
        for (int ks = 0; ks < 6; ks++) {
            short8 bf = *(const short8*)&wsb[rB * 192 + (((ks * 4 + q) ^ (rB & 7)) * 8)];
            a1 = __builtin_amdgcn_mfma_f32_16x16x32_bf16(af1[ks], bf, a1, 0, 0, 0);
        }
        int n = t * 64 + wq4 * 16 + col;
        float bi = b1[n];
        int oct = n >> 3;
        #pragma unroll
        for (int r4 = 0; r4 < 4; r4++) {
            int row = wm + q * 4 + r4;
            float vv = a1[r4] + bi;
            float u = 0.7978845608f * (vv + 0.044715f * vv * vv * vv);
            float tt = 1.f - 2.f / (__expf(2.f * u) + 1.f);
            vv = 0.5f * vv * (1.f + tt);
            int osw = (oct & ~7) | ((oct ^ row) & 7);
            *(__hip_bfloat16*)((char*)arena + row * 1536 + osw * 16 + (n & 7) * 2) =
                __float2bfloat16(vv);
        }
        __builtin_amdgcn_s_barrier();
    }
    LDS_SYNC();

    f32x4 acc2[3] = {};
    for (int ch = 0; ch < 12; ch++) {
        if (ch < 11) {
            stage_w2(W2, ch + 1, (char*)&Wsb[ch & 1][0], wave, lane);
            asm volatile("s_waitcnt vmcnt(2)" ::: "memory");
        } else {
            asm volatile("s_waitcnt vmcnt(0)" ::: "memory");
        }
        __builtin_amdgcn_s_barrier();
        const __hip_bfloat16* wsb = &Wsb[(ch + 1) & 1][0];
        #pragma unroll
        for (int ks = 0; ks < 2; ks++) {
            int row = wm + col;
            int og = ch * 8 + ks * 4 + q;
            int osw = (og & ~7) | ((og ^ row) & 7);
            short8 a2 = *(const short8*)((char*)arena + row * 1536 + osw * 16);
            #pragma unroll
            for (int f = 0; f < 3; f++) {
                int rB = f * 64 + wq4 * 16 + col;
                short8 bf = *(const short8*)&wsb[rB * 64 + (((ks * 4 + q) ^ (rB & 7)) * 8)];
                acc2[f] = __builtin_amdgcn_mfma_f32_16x16x32_bf16(a2, bf, acc2[f], 0, 0, 0);
            }
        }
        __builtin_amdgcn_s_barrier();
    }

    #pragma unroll
    for (int f = 0; f < 3; f++) {
        int n = f * 64 + wq4 * 16 + col;
        float g = fabsf(gamma2[s * DIM + n]);
        float bi = b2[n];
        #pragma unroll
        for (int r4 = 0; r4 < 4; r4++) {
            int m = m0 + wm + q * 4 + r4;
            outf[(size_t)m * DIM + n] = v[f][r4] + g * (acc2[f][r4] + bi);
        }
    }
}

// ---------------- Neighborhood attention: bf16 K/V, row-batched online softmax ----------------
__device__ __forceinline__ void unpack8(const __hip_bfloat16* ptr, float* f) {
    short8 s8 = *(const short8*)ptr;
    union { short8 v; unsigned u[4]; } c; c.v = s8;
    #pragma unroll
    for (int w = 0; w < 4; w++) {
        f[2*w]   = __uint_as_float(c.u[w] << 16);
        f[2*w+1] = __uint_as_float(c.u[w] & 0xffff0000u);
    }
}

__global__ __launch_bounds__(256, 4) void attn_kernel3(
    const float* __restrict__ qbuf, const __hip_bfloat16* __restrict__ kbuf,
    const __hip_bfloat16* __restrict__ vbuf, const float* __restrict__ rpb,
    __hip_bfloat16* __restrict__ out)
{
    __shared__ __hip_bfloat16 Ks[WIN * WIN * KPAD];
    __shared__ __hip_bfloat16 Vs[WIN * WIN * KPAD];
    __shared__ float rpbs[169];

    int head = blockIdx.y;
    int tile = blockIdx.x;
    int ti0 = (tile >> 4) * 8;
    int tj0 = (tile & 15) * 8;
    int wi0 = ti0 - 3; wi0 = wi0 < 0 ? 0 : (wi0 > IMH - WIN ? IMH - WIN : wi0);
    int wj0 = tj0 - 3; wj0 = wj0 < 0 ? 0 : (wj0 > IMW - WIN ? IMW - WIN : wj0);

    int tid = threadIdx.x;
    const size_t hbase = (size_t)head * NPIX;

    for (int c = tid; c < 784; c += 256) {
        int i = c / 56, part = c - i * 56;
        int n = i * WIN + (part >> 2);
        int dp2 = part & 3;
        size_t goff = (hbase + (size_t)(wi0 + i) * IMW + wj0) * 32 + part * 8;
        short8 kk = *(const short8*)(kbuf + goff);
        short8 vv = *(const short8*)(vbuf + goff);
        *(short8*)&Ks[n * KPAD + dp2 * 8] = kk;
        *(short8*)&Vs[n * KPAD + dp2 * 8] = vv;
    }
    if (tid < 169) rpbs[tid] = rpb[head * 169 + tid];

    int p   = tid >> 2;
    int sub = tid & 3;
    int pi = ti0 + (p >> 3), pj = tj0 + (p & 7);
    int si = pi - 3; si = si < 0 ? 0 : (si > IMH - KSZ ? IMH - KSZ : si);
    int sj = pj - 3; sj = sj < 0 ? 0 : (sj > IMW - KSZ ? IMW - KSZ : sj);
    int bi = si - wi0, bj = sj - wj0;

    const float4* qp = (const float4*)(qbuf + (hbase + (size_t)(pi * IMW + pj)) * 32 + sub * 8);
    float4 q0 = qp[0], q1 = qp[1];
    float q[8] = {q0.x, q0.y, q0.z, q0.w, q1.x, q1.y, q1.z, q1.w};

    __syncthreads();

    float m = -1e30f, l = 0.f;
    float acc[8] = {};
    #pragma unroll
    for (int ki = 0; ki < KSZ; ki++) {
        int rbase = (bi + ki) * WIN + bj;
        const float* rb = &rpbs[(si + ki - pi + 6) * 13 + (sj - pj + 6)];
        float s7[KSZ];
        #pragma unroll
        for (int kj = 0; kj < KSZ; kj++) {
            float kf[8];
            unpack8(&Ks[(rbase + kj) * KPAD + sub * 8], kf);
            float d = q[0]*kf[0] + q[1]*kf[1] + q[2]*kf[2] + q[3]*kf[3]
                    + q[4]*kf[4] + q[5]*kf[5] + q[6]*kf[6] + q[7]*kf[7];
            d += __shfl_xor(d, 1);
            d += __shfl_xor(d, 2);
            s7[kj] = d + rb[kj];
        }
        float rmax = s7[0];
        #pragma unroll
        for (int kj = 1; kj < KSZ; kj++) rmax = fmaxf(rmax, s7[kj]);
        float mn = fmaxf(m, rmax);
        float co = __expf(m - mn);
        l *= co;
        #pragma unroll
        for (int e = 0; e < 8; e++) acc[e] *= co;
        #pragma unroll
        for (int kj = 0; kj < KSZ; kj++) {
            float pw2 = __expf(s7[kj] - mn);
            l += pw2;
            float vf[8];
            unpack8(&Vs[(rbase + kj) * KPAD + sub * 8], vf);
            #pragma unroll
            for (int e = 0; e < 8; e++) acc[e] += pw2 * vf[e];
        }
        m = mn;
    }
    float rl = 1.f / l;
    __hip_bfloat16* op = out + (size_t)(pi * IMW + pj) * DIM + head * HD + sub * 8;
    #pragma unroll
    for (int e = 0; e < 8; e++) op[e] = __float2bfloat16(acc[e] * rl);
}

extern "C" void kernel_launch(void* const* d_in, const int* in_sizes, int n_in,
                              void* d_out, int out_size, void* d_ws, size_t ws_size,
                              hipStream_t stream)
{
    const float* x      = (const float*)d_in[0];
    const float* qkv_w  = (const float*)d_in[1];
    const float* qkv_b  = (const float*)d_in[2];
    const float* proj_w = (const float*)d_in[3];
    const float* proj_b = (const float*)d_in[4];
    const float* rpb    = (const float*)d_in[5];
    const float* ln1_w  = (const float*)d_in[6];
    const float* ln1_b  = (const float*)d_in[7];
    const float* ln2_w  = (const float*)d_in[8];
    const float* ln2_b  = (const float*)d_in[9];
    const float* fc1_w  = (const float*)d_in[10];
    const float* fc1_b  = (const float*)d_in[11];
    const float* fc2_w  = (const float*)d_in[12];
    const float* fc2_b  = (const float*)d_in[13];
    const float* gamma1 = (const float*)d_in[14];
    const float* gamma2 = (const float*)d_in[15];
    const int*   quality= (const int*)d_in[16];
    float* out = (float*)d_out;

    char* ws = (char*)d_ws;
    float*          qbuf   = (float*)ws;                         // 12.58 MB
    __hip_bfloat16* kbuf   = (__hip_bfloat16*)(ws + 12582912);   // 6.29 MB
    __hip_bfloat16* vbuf   = (__hip_bfloat16*)(ws + 18874368);   // 6.29 MB
    __hip_bfloat16* attn_b = (__hip_bfloat16*)(ws + 44040192);
    __hip_bfloat16* wp     = (__hip_bfloat16*)(ws + 50552832);
    __hip_bfloat16* wf1    = (__hip_bfloat16*)(ws + 50626560);
    __hip_bfloat16* wf2    = (__hip_bfloat16*)(ws + 50921472);

    // 1. QKV GEMM (fused LN1, inline wq cvt) + piggyback cvt of wp/wf1/wf2 for the tail
    qkv_ln_gemm<<<512 + 324, 256, 0, stream>>>(
        x, ln1_w, ln1_b, qkv_w, qkv_b, qbuf, kbuf, vbuf,
        proj_w, fc1_w, fc2_w, wp, wf1, wf2);
    // 2. neighborhood attention -> attn_b (bf16)
    attn_kernel3<<<dim3(256, NHD), 256, 0, stream>>>(qbuf, kbuf, vbuf, rpb, attn_b);
    // 3. fused tail (16 waves): proj + resid + |g1| + LN2 + FC1 + GELU + FC2 + resid + |g2|
    tail_fused<<<256, 1024, 0, stream>>>(
        attn_b, wp, proj_b, x, gamma1, ln2_w, ln2_b,
        wf1, fc1_b, wf2, fc2_b, gamma2, quality, out);
}

// Round 7
// 170.608 us; speedup vs baseline: 1.0084x; 1.0084x over previous
//
#include <hip/hip_runtime.h>
#include <hip/hip_bf16.h>
#include <math.h>

#define DIM 192
#define NHD 6
#define HD 32
#define KSZ 7
#define HID 768
#define IMH 128
#define IMW 128
#define NPIX (IMH*IMW)
#define WIN 14
#define KPAD 40

typedef __attribute__((ext_vector_type(8))) short short8;
typedef __attribute__((ext_vector_type(4))) float f32x4;

#define LDS_SYNC() do { \
    asm volatile("s_waitcnt lgkmcnt(0)" ::: "memory"); \
    __builtin_amdgcn_sched_barrier(0); \
    __builtin_amdgcn_s_barrier(); } while (0)

// ---------------- qkv weight fp32->bf16 (108 blocks; wp/wf1/wf2 ride in the attn launch) ----------------
__global__ __launch_bounds__(256) void cvt_w(
    const float* __restrict__ qw, __hip_bfloat16* __restrict__ dq)
{
    int idx = blockIdx.x * 1024 + threadIdx.x * 4;
    float4 v4 = *(const float4*)(qw + idx);
    union { ushort4 u; __hip_bfloat16 h[4]; } o;
    o.h[0] = __float2bfloat16(v4.x); o.h[1] = __float2bfloat16(v4.y);
    o.h[2] = __float2bfloat16(v4.z); o.h[3] = __float2bfloat16(v4.w);
    *(ushort4*)&dq[idx] = o.u;
}

__device__ __forceinline__ void gl_lds16(const void* g, void* l) {
    __builtin_amdgcn_global_load_lds(
        (const __attribute__((address_space(1))) void*)g,
        (__attribute__((address_space(3))) void*)l, 16, 0, 0);
}

__device__ __forceinline__ short8 cvt8(float4 a, float4 b) {
    union { short8 v; __hip_bfloat16 h[8]; } u;
    u.h[0] = __float2bfloat16(a.x); u.h[1] = __float2bfloat16(a.y);
    u.h[2] = __float2bfloat16(a.z); u.h[3] = __float2bfloat16(a.w);
    u.h[4] = __float2bfloat16(b.x); u.h[5] = __float2bfloat16(b.y);
    u.h[6] = __float2bfloat16(b.z); u.h[7] = __float2bfloat16(b.w);
    return u.v;
}

// ---- 1024-thread staging: 64 rows x 192 K (1536 slots of 16B), 96 slots/wave,
// exactly 2 VMEM issues per wave (2nd exec-masked to 32 lanes) -> uniform vmcnt.
__device__ __forceinline__ void stage_rows(const __hip_bfloat16* __restrict__ src,
                                           char* ldsbase, int wave, int lane) {
    int c0 = wave * 96 + lane;
    int r0 = c0 / 24, k0 = c0 - r0 * 24;
    gl_lds16(src + (size_t)r0 * DIM + ((k0 ^ (r0 & 7)) * 8), ldsbase + (wave * 96) * 16);
    int c1 = wave * 96 + 64 + (lane & 31);
    int r1 = c1 / 24, k1 = c1 - r1 * 24;
    if (lane < 32)
        gl_lds16(src + (size_t)r1 * DIM + ((k1 ^ (r1 & 7)) * 8), ldsbase + (wave * 96 + 64) * 16);
}
// ---- FC2 weight chunk: 192 n-rows x 64 K (8 slots/row), same 96-slot/wave split
__device__ __forceinline__ void stage_w2(const __hip_bfloat16* __restrict__ W2, int ch,
                                         char* ldsbase, int wave, int lane) {
    int i0 = wave * 96 + lane;
    int r0 = i0 >> 3, o0 = i0 & 7;
    gl_lds16(W2 + (size_t)r0 * HID + ch * 64 + ((o0 ^ (r0 & 7)) * 8), ldsbase + (wave * 96) * 16);
    int i1 = wave * 96 + 64 + (lane & 31);
    int r1 = i1 >> 3, o1 = i1 & 7;
    if (lane < 32)
        gl_lds16(W2 + (size_t)r1 * HID + ch * 64 + ((o1 ^ (r1 & 7)) * 8), ldsbase + (wave * 96 + 64) * 16);
}

// ---------------- QKV GEMM with fused LN1: 32 rows x full 576 cols per block ----------------
// SINGLE-buffer weights (24 KB) -> 36 KB LDS total -> 4 blocks/CU (16 waves/CU).
// Cross-block TLP hides the per-chunk stage latency (m114 wave-level overlap) instead of
// intra-block double-buffering. Counted vmcnt(8): 6 stage loads issued before 8 epilogue
// stores; FIFO retirement means vmcnt(8) waits exactly for the 6 loads.
__global__ __launch_bounds__(256, 4) void qkv_ln_gemm(
    const float* __restrict__ x, const float* __restrict__ lnw, const float* __restrict__ lnb,
    const __hip_bfloat16* __restrict__ W, const float* __restrict__ bias,
    float* __restrict__ qb, __hip_bfloat16* __restrict__ kb, __hip_bfloat16* __restrict__ vb)
{
    __shared__ __hip_bfloat16 As[32 * 192];   // 12 KB
    __shared__ __hip_bfloat16 Ws[64 * 192];   // 24 KB (single buffer)
    int tid = threadIdx.x;
    int wave = tid >> 6, lane = tid & 63;
    int q = lane >> 4, col = lane & 15;
    int wm = (wave >> 1) * 16, wn = (wave & 1) * 32;
    int m0 = blockIdx.x * 32;

    auto stageW = [&](int ch) {   // 64 n-rows x 192 K, 6 gl_lds per thread
        #pragma unroll
        for (int i = 0; i < 6; i++) {
            int c = i * 256 + tid;
            int r = c / 24, kc = c - r * 24;
            gl_lds16(W + (size_t)(ch * 64 + r) * DIM + ((kc ^ (r & 7)) * 8),
                     (char*)&Ws[0] + (i * 256 + wave * 64) * 16);
        }
    };

    stageW(0);   // chunk-0 weights fly under LN1 compute

    // ---- LN1: 8 lanes per row, 24 cols each ----
    {
        int row = tid >> 3, sub = tid & 7;
        const float4* xr = (const float4*)(x + (size_t)(m0 + row) * DIM + sub * 24);
        float4 xa[6];
        float s = 0.f;
        #pragma unroll
        for (int i = 0; i < 6; i++) {
            xa[i] = xr[i];
            s += xa[i].x + xa[i].y + xa[i].z + xa[i].w;
        }
        s += __shfl_xor(s, 1); s += __shfl_xor(s, 2); s += __shfl_xor(s, 4);
        float mu = s * (1.0f / DIM);
        float qs = 0.f;
        #pragma unroll
        for (int i = 0; i < 6; i++) {
            float a = xa[i].x - mu, b = xa[i].y - mu, c = xa[i].z - mu, d = xa[i].w - mu;
            qs += a * a + b * b + c * c + d * d;
        }
        qs += __shfl_xor(qs, 1); qs += __shfl_xor(qs, 2); qs += __shfl_xor(qs, 4);
        float rstd = rsqrtf(qs * (1.0f / DIM) + 1e-5f);
        const float4* wv = (const float4*)(lnw + sub * 24);
        const float4* bv = (const float4*)(lnb + sub * 24);
        #pragma unroll
        for (int j = 0; j < 3; j++) {
            float4 v0 = xa[j * 2], v1 = xa[j * 2 + 1];
            float4 w0 = wv[j * 2], w1 = wv[j * 2 + 1];
            float4 b0 = bv[j * 2], b1 = bv[j * 2 + 1];
            float4 o0, o1;
            o0.x = (v0.x - mu) * rstd * w0.x + b0.x;
            o0.y = (v0.y - mu) * rstd * w0.y + b0.y;
            o0.z = (v0.z - mu) * rstd * w0.z + b0.z;
            o0.w = (v0.w - mu) * rstd * w0.w + b0.w;
            o1.x = (v1.x - mu) * rstd * w1.x + b1.x;
            o1.y = (v1.y - mu) * rstd * w1.y + b1.y;
            o1.z = (v1.z - mu) * rstd * w1.z + b1.z;
            o1.w = (v1.w - mu) * rstd * w1.w + b1.w;
            int oct = sub * 3 + j;
            *(short8*)&As[row * 192 + ((oct ^ (row & 7)) * 8)] = cvt8(o0, o1);
        }
    }
    asm volatile("s_waitcnt vmcnt(0) lgkmcnt(0)" ::: "memory"); // Ws chunk0 + As writes done
    __builtin_amdgcn_sched_barrier(0);
    __builtin_amdgcn_s_barrier();

    short8 af[6];
    {
        int rA = wm + col;
        #pragma unroll
        for (int ks = 0; ks < 6; ks++)
            af[ks] = *(const short8*)&As[rA * 192 + (((ks * 4 + q) ^ (rA & 7)) * 8)];
    }

    for (int ch = 0; ch < 9; ch++) {
        f32x4 acc[2] = {};
        #pragma unroll
        for (int ks = 0; ks < 6; ks++) {
            #pragma unroll
            for (int ni = 0; ni < 2; ni++) {
                int rB = wn + ni * 16 + col;
                short8 bf = *(const short8*)&Ws[rB * 192 + (((ks * 4 + q) ^ (rB & 7)) * 8)];
                acc[ni] = __builtin_amdgcn_mfma_f32_16x16x32_bf16(af[ks], bf, acc[ni], 0, 0, 0);
            }
        }
        asm volatile("s_waitcnt lgkmcnt(0)" ::: "memory");  // my Ws reads done
        __builtin_amdgcn_sched_barrier(0);
        __builtin_amdgcn_s_barrier();                        // Ws consumed block-wide
        if (ch < 8) stageW(ch + 1);                          // issue next-chunk loads
        #pragma unroll
        for (int ni = 0; ni < 2; ni++) {                     // 8 stores overlap the loads
            int n = ch * 64 + wn + ni * 16 + col;
            float bi = bias[n];
            int h18 = n >> 5;
            int sel = h18 / 6;
            int head = h18 - sel * 6;
            #pragma unroll
            for (int r4 = 0; r4 < 4; r4++) {
                int m = m0 + wm + q * 4 + r4;
                float v = acc[ni][r4] + bi;
                size_t idx = ((size_t)head * NPIX + m) * 32 + (n & 31);
                if (sel == 0)      qb[idx] = v * 0.17677669529663687f;
                else if (sel == 1) kb[idx] = __float2bfloat16(v);
                else               vb[idx] = __float2bfloat16(v);
            }
        }
        if (ch < 8) {
            asm volatile("s_waitcnt vmcnt(8)" ::: "memory"); // 6 loads retired (8 stores may linger)
            __builtin_amdgcn_s_barrier();
        }
    }
}

// ---------------- fused tail, 16 waves (unchanged, r4-proven) ----------------
__global__ __launch_bounds__(1024, 4) void tail_fused(
    const __hip_bfloat16* __restrict__ A, const __hip_bfloat16* __restrict__ Wp,
    const float* __restrict__ pb, const float* __restrict__ resid,
    const float* __restrict__ gamma1, const float* __restrict__ ln2w, const float* __restrict__ ln2b,
    const __hip_bfloat16* __restrict__ W1, const float* __restrict__ b1,
    const __hip_bfloat16* __restrict__ W2, const float* __restrict__ b2,
    const float* __restrict__ gamma2, const int* __restrict__ quality,
    float* __restrict__ outf)
{
    __shared__ __hip_bfloat16 arena[64 * 768];     // 96 KB: Ms; top 24 KB doubles as Hs
    __shared__ __hip_bfloat16 Wsb[2][64 * 192];    // 2 x 24 KB
    __shared__ float lnred[4][64][2];              // 2 KB
    __hip_bfloat16* Hs = arena + 36864;            // 24 KB

    int tid = threadIdx.x;
    int wave = tid >> 6, lane = tid & 63;
    int q = lane >> 4, col = lane & 15;
    int wm = (wave >> 2) * 16, wq4 = wave & 3;
    int m0 = blockIdx.x * 64;
    int s = quality[0] - 1;

    stage_rows(A + (size_t)m0 * DIM, (char*)Hs, wave, lane);
    stage_rows(Wp, (char*)&Wsb[0][0], wave, lane);
    stage_rows(Wp + 64 * DIM, (char*)&Wsb[1][0], wave, lane);
    asm volatile("s_waitcnt vmcnt(2)" ::: "memory");
    __builtin_amdgcn_s_barrier();

    short8 afp[6];
    {
        int rA = wm + col;
        #pragma unroll
        for (int ks = 0; ks < 6; ks++)
            afp[ks] = *(const short8*)&Hs[rA * 192 + (((ks * 4 + q) ^ (rA & 7)) * 8)];
    }

    float v[3][4];
    float sm[4] = {}, sq[4] = {};
    auto proj_chunk = [&](int ch, const __hip_bfloat16* wsb) {
        f32x4 pacc = {};
        int rB = wq4 * 16 + col;
        #pragma unroll
        for (int ks = 0; ks < 6; ks++) {
            short8 bf = *(const short8*)&wsb[rB * 192 + (((ks * 4 + q) ^ (rB & 7)) * 8)];
            pacc = __builtin_amdgcn_mfma_f32_16x16x32_bf16(afp[ks], bf, pacc, 0, 0, 0);
        }
        int n = ch * 64 + wq4 * 16 + col;
        float bi = pb[n];
        float g = fabsf(gamma1[s * DIM + n]);
        #pragma unroll
        for (int r = 0; r < 4; r++) {
            int m = m0 + wm + q * 4 + r;
            v[ch][r] = resid[(size_t)m * DIM + n] + g * (pacc[r] + bi);
            sm[r] += v[ch][r]; sq[r] += v[ch][r] * v[ch][r];
        }
    };

    proj_chunk(0, &Wsb[0][0]);
    __builtin_amdgcn_s_barrier();
    stage_rows(Wp + 128 * DIM, (char*)&Wsb[0][0], wave, lane);
    asm volatile("s_waitcnt vmcnt(2)" ::: "memory");
    __builtin_amdgcn_s_barrier();
    proj_chunk(1, &Wsb[1][0]);
    __builtin_amdgcn_s_barrier();
    stage_rows(W1, (char*)&Wsb[1][0], wave, lane);
    asm volatile("s_waitcnt vmcnt(2)" ::: "memory");
    __builtin_amdgcn_s_barrier();
    proj_chunk(2, &Wsb[0][0]);

    #pragma unroll
    for (int off = 1; off <= 8; off <<= 1)
        #pragma unroll
        for (int r = 0; r < 4; r++) {
            sm[r] += __shfl_xor(sm[r], off);
            sq[r] += __shfl_xor(sq[r], off);
        }
    if (col == 0) {
        #pragma unroll
        for (int r = 0; r < 4; r++) {
            lnred[wq4][wm + q * 4 + r][0] = sm[r];
            lnred[wq4][wm + q * 4 + r][1] = sq[r];
        }
    }
    LDS_SYNC();
    float mu[4], rstd[4];
    #pragma unroll
    for (int r = 0; r < 4; r++) {
        int ml = wm + q * 4 + r;
        float smt = lnred[0][ml][0] + lnred[1][ml][0] + lnred[2][ml][0] + lnred[3][ml][0];
        float sqt = lnred[0][ml][1] + lnred[1][ml][1] + lnred[2][ml][1] + lnred[3][ml][1];
        mu[r] = smt * (1.0f / DIM);
        float var = sqt * (1.0f / DIM) - mu[r] * mu[r];
        rstd[r] = rsqrtf(var + 1e-5f);
    }
    #pragma unroll
    for (int ch = 0; ch < 3; ch++) {
        int n = ch * 64 + wq4 * 16 + col;
        float lw = ln2w[n], lb = ln2b[n];
        #pragma unroll
        for (int r = 0; r < 4; r++) {
            int ml = wm + q * 4 + r;
            Hs[ml * 192 + (((n >> 3) ^ (ml & 7)) * 8) + (n & 7)] =
                __float2bfloat16((v[ch][r] - mu[r]) * rstd[r] * lw + lb);
        }
    }
    LDS_SYNC();
    short8 af1[6];
    {
        int rowA = wm + col;
        #pragma unroll
        for (int ks = 0; ks < 6; ks++)
            af1[ks] = *(const short8*)&Hs[rowA * 192 + (((ks * 4 + q) ^ (rowA & 7)) * 8)];
    }
    LDS_SYNC();

    for (int t = 0; t < 12; t++) {
        if (t < 11) stage_rows(W1 + (size_t)(t + 1) * 64 * DIM, (char*)&Wsb[t & 1][0], wave, lane);
        else        stage_w2(W2, 0, (char*)&Wsb[1][0], wave, lane);
        asm volatile("s_waitcnt vmcnt(2)" ::: "memory");
        __builtin_amdgcn_s_barrier();
        const __hip_bfloat16* wsb = &Wsb[(t + 1) & 1][0];
        f32x4 a1 = {};
        int rB = wq4 * 16 + col;
        #pragma unroll
        for (int ks = 0; ks < 6; ks++) {
            short8 bf = *(const short8*)&wsb[rB * 192 + (((ks * 4 + q) ^ (rB & 7)) * 8)];
            a1 = __builtin_amdgcn_mfma_f32_16x16x32_bf16(af1[ks], bf, a1, 0, 0, 0);
        }
        int n = t * 64 + wq4 * 16 + col;
        float bi = b1[n];
        int oct = n >> 3;
        #pragma unroll
        for (int r4 = 0; r4 < 4; r4++) {
            int row = wm + q * 4 + r4;
            float vv = a1[r4] + bi;
            float u = 0.7978845608f * (vv + 0.044715f * vv * vv * vv);
            float tt = 1.f - 2.f / (__expf(2.f * u) + 1.f);
            vv = 0.5f * vv * (1.f + tt);
            int osw = (oct & ~7) | ((oct ^ row) & 7);
            *(__hip_bfloat16*)((char*)arena + row * 1536 + osw * 16 + (n & 7) * 2) =
                __float2bfloat16(vv);
        }
        __builtin_amdgcn_s_barrier();
    }
    LDS_SYNC();

    f32x4 acc2[3] = {};
    for (int ch = 0; ch < 12; ch++) {
        if (ch < 11) {
            stage_w2(W2, ch + 1, (char*)&Wsb[ch & 1][0], wave, lane);
            asm volatile("s_waitcnt vmcnt(2)" ::: "memory");
        } else {
            asm volatile("s_waitcnt vmcnt(0)" ::: "memory");
        }
        __builtin_amdgcn_s_barrier();
        const __hip_bfloat16* wsb = &Wsb[(ch + 1) & 1][0];
        #pragma unroll
        for (int ks = 0; ks < 2; ks++) {
            int row = wm + col;
            int og = ch * 8 + ks * 4 + q;
            int osw = (og & ~7) | ((og ^ row) & 7);
            short8 a2 = *(const short8*)((char*)arena + row * 1536 + osw * 16);
            #pragma unroll
            for (int f = 0; f < 3; f++) {
                int rB = f * 64 + wq4 * 16 + col;
                short8 bf = *(const short8*)&wsb[rB * 64 + (((ks * 4 + q) ^ (rB & 7)) * 8)];
                acc2[f] = __builtin_amdgcn_mfma_f32_16x16x32_bf16(a2, bf, acc2[f], 0, 0, 0);
            }
        }
        __builtin_amdgcn_s_barrier();
    }

    #pragma unroll
    for (int f = 0; f < 3; f++) {
        int n = f * 64 + wq4 * 16 + col;
        float g = fabsf(gamma2[s * DIM + n]);
        float bi = b2[n];
        #pragma unroll
        for (int r4 = 0; r4 < 4; r4++) {
            int m = m0 + wm + q * 4 + r4;
            outf[(size_t)m * DIM + n] = v[f][r4] + g * (acc2[f][r4] + bi);
        }
    }
}

// ---------------- Neighborhood attention (+ piggybacked wp/wf1/wf2 cvt blocks) ----------------
__device__ __forceinline__ void unpack8(const __hip_bfloat16* ptr, float* f) {
    short8 s8 = *(const short8*)ptr;
    union { short8 v; unsigned u[4]; } c; c.v = s8;
    #pragma unroll
    for (int w = 0; w < 4; w++) {
        f[2*w]   = __uint_as_float(c.u[w] << 16);
        f[2*w+1] = __uint_as_float(c.u[w] & 0xffff0000u);
    }
}

__global__ __launch_bounds__(256, 4) void attn_kernel3(
    const float* __restrict__ qbuf, const __hip_bfloat16* __restrict__ kbuf,
    const __hip_bfloat16* __restrict__ vbuf, const float* __restrict__ rpb,
    __hip_bfloat16* __restrict__ out,
    const float* __restrict__ pw, const float* __restrict__ f1w, const float* __restrict__ f2w,
    __hip_bfloat16* __restrict__ dp, __hip_bfloat16* __restrict__ df1, __hip_bfloat16* __restrict__ df2)
{
    if (blockIdx.x >= 256) {
        // weight-cvt blocks, hidden under attention (outputs needed only by tail_fused)
        if (blockIdx.y != 0) return;
        int blk = blockIdx.x - 256, t = threadIdx.x;
        const float* s; __hip_bfloat16* d; int base;
        if (blk < 36)       { s = pw;  d = dp;  base = blk * 1024; }
        else if (blk < 180) { s = f1w; d = df1; base = (blk - 36) * 1024; }
        else                { s = f2w; d = df2; base = (blk - 180) * 1024; }
        int idx = base + t * 4;
        float4 v4 = *(const float4*)(s + idx);
        union { ushort4 u; __hip_bfloat16 h[4]; } o;
        o.h[0] = __float2bfloat16(v4.x); o.h[1] = __float2bfloat16(v4.y);
        o.h[2] = __float2bfloat16(v4.z); o.h[3] = __float2bfloat16(v4.w);
        *(ushort4*)&d[idx] = o.u;
        return;
    }

    __shared__ __hip_bfloat16 Ks[WIN * WIN * KPAD];
    __shared__ __hip_bfloat16 Vs[WIN * WIN * KPAD];
    __shared__ float rpbs[169];

    int head = blockIdx.y;
    int tile = blockIdx.x;
    int ti0 = (tile >> 4) * 8;
    int tj0 = (tile & 15) * 8;
    int wi0 = ti0 - 3; wi0 = wi0 < 0 ? 0 : (wi0 > IMH - WIN ? IMH - WIN : wi0);
    int wj0 = tj0 - 3; wj0 = wj0 < 0 ? 0 : (wj0 > IMW - WIN ? IMW - WIN : wj0);

    int tid = threadIdx.x;
    const size_t hbase = (size_t)head * NPIX;

    for (int c = tid; c < 784; c += 256) {
        int i = c / 56, part = c - i * 56;
        int n = i * WIN + (part >> 2);
        int dp2 = part & 3;
        size_t goff = (hbase + (size_t)(wi0 + i) * IMW + wj0) * 32 + part * 8;
        short8 kk = *(const short8*)(kbuf + goff);
        short8 vv = *(const short8*)(vbuf + goff);
        *(short8*)&Ks[n * KPAD + dp2 * 8] = kk;
        *(short8*)&Vs[n * KPAD + dp2 * 8] = vv;
    }
    if (tid < 169) rpbs[tid] = rpb[head * 169 + tid];

    int p   = tid >> 2;
    int sub = tid & 3;
    int pi = ti0 + (p >> 3), pj = tj0 + (p & 7);
    int si = pi - 3; si = si < 0 ? 0 : (si > IMH - KSZ ? IMH - KSZ : si);
    int sj = pj - 3; sj = sj < 0 ? 0 : (sj > IMW - KSZ ? IMW - KSZ : sj);
    int bi = si - wi0, bj = sj - wj0;

    const float4* qp = (const float4*)(qbuf + (hbase + (size_t)(pi * IMW + pj)) * 32 + sub * 8);
    float4 q0 = qp[0], q1 = qp[1];
    float q[8] = {q0.x, q0.y, q0.z, q0.w, q1.x, q1.y, q1.z, q1.w};

    __syncthreads();

    float m = -1e30f, l = 0.f;
    float acc[8] = {};
    #pragma unroll
    for (int ki = 0; ki < KSZ; ki++) {
        int rbase = (bi + ki) * WIN + bj;
        const float* rb = &rpbs[(si + ki - pi + 6) * 13 + (sj - pj + 6)];
        float s7[KSZ];
        #pragma unroll
        for (int kj = 0; kj < KSZ; kj++) {
            float kf[8];
            unpack8(&Ks[(rbase + kj) * KPAD + sub * 8], kf);
            float d = q[0]*kf[0] + q[1]*kf[1] + q[2]*kf[2] + q[3]*kf[3]
                    + q[4]*kf[4] + q[5]*kf[5] + q[6]*kf[6] + q[7]*kf[7];
            d += __shfl_xor(d, 1);
            d += __shfl_xor(d, 2);
            s7[kj] = d + rb[kj];
        }
        float rmax = s7[0];
        #pragma unroll
        for (int kj = 1; kj < KSZ; kj++) rmax = fmaxf(rmax, s7[kj]);
        float mn = fmaxf(m, rmax);
        float co = __expf(m - mn);
        l *= co;
        #pragma unroll
        for (int e = 0; e < 8; e++) acc[e] *= co;
        #pragma unroll
        for (int kj = 0; kj < KSZ; kj++) {
            float pw2 = __expf(s7[kj] - mn);
            l += pw2;
            float vf[8];
            unpack8(&Vs[(rbase + kj) * KPAD + sub * 8], vf);
            #pragma unroll
            for (int e = 0; e < 8; e++) acc[e] += pw2 * vf[e];
        }
        m = mn;
    }
    float rl = 1.f / l;
    __hip_bfloat16* op = out + (size_t)(pi * IMW + pj) * DIM + head * HD + sub * 8;
    #pragma unroll
    for (int e = 0; e < 8; e++) op[e] = __float2bfloat16(acc[e] * rl);
}

extern "C" void kernel_launch(void* const* d_in, const int* in_sizes, int n_in,
                              void* d_out, int out_size, void* d_ws, size_t ws_size,
                              hipStream_t stream)
{
    const float* x      = (const float*)d_in[0];
    const float* qkv_w  = (const float*)d_in[1];
    const float* qkv_b  = (const float*)d_in[2];
    const float* proj_w = (const float*)d_in[3];
    const float* proj_b = (const float*)d_in[4];
    const float* rpb    = (const float*)d_in[5];
    const float* ln1_w  = (const float*)d_in[6];
    const float* ln1_b  = (const float*)d_in[7];
    const float* ln2_w  = (const float*)d_in[8];
    const float* ln2_b  = (const float*)d_in[9];
    const float* fc1_w  = (const float*)d_in[10];
    const float* fc1_b  = (const float*)d_in[11];
    const float* fc2_w  = (const float*)d_in[12];
    const float* fc2_b  = (const float*)d_in[13];
    const float* gamma1 = (const float*)d_in[14];
    const float* gamma2 = (const float*)d_in[15];
    const int*   quality= (const int*)d_in[16];
    float* out = (float*)d_out;

    char* ws = (char*)d_ws;
    float*          qbuf   = (float*)ws;                         // 12.58 MB
    __hip_bfloat16* kbuf   = (__hip_bfloat16*)(ws + 12582912);   // 6.29 MB
    __hip_bfloat16* vbuf   = (__hip_bfloat16*)(ws + 18874368);   // 6.29 MB
    __hip_bfloat16* attn_b = (__hip_bfloat16*)(ws + 44040192);
    __hip_bfloat16* wq     = (__hip_bfloat16*)(ws + 50331648);
    __hip_bfloat16* wp     = (__hip_bfloat16*)(ws + 50552832);
    __hip_bfloat16* wf1    = (__hip_bfloat16*)(ws + 50626560);
    __hip_bfloat16* wf2    = (__hip_bfloat16*)(ws + 50921472);

    // 0. qkv weights->bf16 (108 blocks)
    cvt_w<<<108, 256, 0, stream>>>(qkv_w, wq);
    // 1. QKV GEMM with fused LN1 (single-buffer Ws, 4 blocks/CU)
    qkv_ln_gemm<<<512, 256, 0, stream>>>(
        x, ln1_w, ln1_b, wq, qkv_b, qbuf, kbuf, vbuf);
    // 2. neighborhood attention (+324 piggyback blocks converting wp/wf1/wf2)
    attn_kernel3<<<dim3(256 + 324, NHD), 256, 0, stream>>>(
        qbuf, kbuf, vbuf, rpb, attn_b, proj_w, fc1_w, fc2_w, wp, wf1, wf2);
    // 3. fused tail (16 waves): proj + resid + |g1| + LN2 + FC1 + GELU + FC2 + resid + |g2|
    tail_fused<<<256, 1024, 0, stream>>>(
        attn_b, wp, proj_b, x, gamma1, ln2_w, ln2_b,
        wf1, fc1_b, wf2, fc2_b, gamma2, quality, out);
}

// Round 8
// 167.804 us; speedup vs baseline: 1.0253x; 1.0167x over previous
//
#include <hip/hip_runtime.h>
#include <hip/hip_bf16.h>
#include <math.h>

#define DIM 192
#define NHD 6
#define HD 32
#define KSZ 7
#define HID 768
#define IMH 128
#define IMW 128
#define NPIX (IMH*IMW)
#define WIN 14
#define KPAD 40

typedef __attribute__((ext_vector_type(8))) short short8;
typedef __attribute__((ext_vector_type(4))) float f32x4;

#define LDS_SYNC() do { \
    asm volatile("s_waitcnt lgkmcnt(0)" ::: "memory"); \
    __builtin_amdgcn_sched_barrier(0); \
    __builtin_amdgcn_s_barrier(); } while (0)

// ---------------- qkv weight fp32->bf16 (108 blocks; wp/wf1/wf2 ride in the attn launch) ----------------
__global__ __launch_bounds__(256) void cvt_w(
    const float* __restrict__ qw, __hip_bfloat16* __restrict__ dq)
{
    int idx = blockIdx.x * 1024 + threadIdx.x * 4;
    float4 v4 = *(const float4*)(qw + idx);
    union { ushort4 u; __hip_bfloat16 h[4]; } o;
    o.h[0] = __float2bfloat16(v4.x); o.h[1] = __float2bfloat16(v4.y);
    o.h[2] = __float2bfloat16(v4.z); o.h[3] = __float2bfloat16(v4.w);
    *(ushort4*)&dq[idx] = o.u;
}

__device__ __forceinline__ void gl_lds16(const void* g, void* l) {
    __builtin_amdgcn_global_load_lds(
        (const __attribute__((address_space(1))) void*)g,
        (__attribute__((address_space(3))) void*)l, 16, 0, 0);
}

__device__ __forceinline__ short8 cvt8(float4 a, float4 b) {
    union { short8 v; __hip_bfloat16 h[8]; } u;
    u.h[0] = __float2bfloat16(a.x); u.h[1] = __float2bfloat16(a.y);
    u.h[2] = __float2bfloat16(a.z); u.h[3] = __float2bfloat16(a.w);
    u.h[4] = __float2bfloat16(b.x); u.h[5] = __float2bfloat16(b.y);
    u.h[6] = __float2bfloat16(b.z); u.h[7] = __float2bfloat16(b.w);
    return u.v;
}

// ---- 1024-thread staging: 64 rows x 192 K (1536 slots of 16B), 96 slots/wave
__device__ __forceinline__ void stage_rows(const __hip_bfloat16* __restrict__ src,
                                           char* ldsbase, int wave, int lane) {
    int c0 = wave * 96 + lane;
    int r0 = c0 / 24, k0 = c0 - r0 * 24;
    gl_lds16(src + (size_t)r0 * DIM + ((k0 ^ (r0 & 7)) * 8), ldsbase + (wave * 96) * 16);
    int c1 = wave * 96 + 64 + (lane & 31);
    int r1 = c1 / 24, k1 = c1 - r1 * 24;
    if (lane < 32)
        gl_lds16(src + (size_t)r1 * DIM + ((k1 ^ (r1 & 7)) * 8), ldsbase + (wave * 96 + 64) * 16);
}
__device__ __forceinline__ void stage_w2(const __hip_bfloat16* __restrict__ W2, int ch,
                                         char* ldsbase, int wave, int lane) {
    int i0 = wave * 96 + lane;
    int r0 = i0 >> 3, o0 = i0 & 7;
    gl_lds16(W2 + (size_t)r0 * HID + ch * 64 + ((o0 ^ (r0 & 7)) * 8), ldsbase + (wave * 96) * 16);
    int i1 = wave * 96 + 64 + (lane & 31);
    int r1 = i1 >> 3, o1 = i1 & 7;
    if (lane < 32)
        gl_lds16(W2 + (size_t)r1 * HID + ch * 64 + ((o1 ^ (r1 & 7)) * 8), ldsbase + (wave * 96 + 64) * 16);
}

// ---------------- QKV GEMM with fused LN1 (r6 config: single-buffer Ws, 4 blocks/CU) ----------------
__global__ __launch_bounds__(256, 4) void qkv_ln_gemm(
    const float* __restrict__ x, const float* __restrict__ lnw, const float* __restrict__ lnb,
    const __hip_bfloat16* __restrict__ W, const float* __restrict__ bias,
    float* __restrict__ qb, __hip_bfloat16* __restrict__ kb, __hip_bfloat16* __restrict__ vb)
{
    __shared__ __hip_bfloat16 As[32 * 192];   // 12 KB
    __shared__ __hip_bfloat16 Ws[64 * 192];   // 24 KB (single buffer)
    int tid = threadIdx.x;
    int wave = tid >> 6, lane = tid & 63;
    int q = lane >> 4, col = lane & 15;
    int wm = (wave >> 1) * 16, wn = (wave & 1) * 32;
    int m0 = blockIdx.x * 32;

    auto stageW = [&](int ch) {
        #pragma unroll
        for (int i = 0; i < 6; i++) {
            int c = i * 256 + tid;
            int r = c / 24, kc = c - r * 24;
            gl_lds16(W + (size_t)(ch * 64 + r) * DIM + ((kc ^ (r & 7)) * 8),
                     (char*)&Ws[0] + (i * 256 + wave * 64) * 16);
        }
    };

    stageW(0);

    {
        int row = tid >> 3, sub = tid & 7;
        const float4* xr = (const float4*)(x + (size_t)(m0 + row) * DIM + sub * 24);
        float4 xa[6];
        float s = 0.f;
        #pragma unroll
        for (int i = 0; i < 6; i++) {
            xa[i] = xr[i];
            s += xa[i].x + xa[i].y + xa[i].z + xa[i].w;
        }
        s += __shfl_xor(s, 1); s += __shfl_xor(s, 2); s += __shfl_xor(s, 4);
        float mu = s * (1.0f / DIM);
        float qs = 0.f;
        #pragma unroll
        for (int i = 0; i < 6; i++) {
            float a = xa[i].x - mu, b = xa[i].y - mu, c = xa[i].z - mu, d = xa[i].w - mu;
            qs += a * a + b * b + c * c + d * d;
        }
        qs += __shfl_xor(qs, 1); qs += __shfl_xor(qs, 2); qs += __shfl_xor(qs, 4);
        float rstd = rsqrtf(qs * (1.0f / DIM) + 1e-5f);
        const float4* wv = (const float4*)(lnw + sub * 24);
        const float4* bv = (const float4*)(lnb + sub * 24);
        #pragma unroll
        for (int j = 0; j < 3; j++) {
            float4 v0 = xa[j * 2], v1 = xa[j * 2 + 1];
            float4 w0 = wv[j * 2], w1 = wv[j * 2 + 1];
            float4 b0 = bv[j * 2], b1 = bv[j * 2 + 1];
            float4 o0, o1;
            o0.x = (v0.x - mu) * rstd * w0.x + b0.x;
            o0.y = (v0.y - mu) * rstd * w0.y + b0.y;
            o0.z = (v0.z - mu) * rstd * w0.z + b0.z;
            o0.w = (v0.w - mu) * rstd * w0.w + b0.w;
            o1.x = (v1.x - mu) * rstd * w1.x + b1.x;
            o1.y = (v1.y - mu) * rstd * w1.y + b1.y;
            o1.z = (v1.z - mu) * rstd * w1.z + b1.z;
            o1.w = (v1.w - mu) * rstd * w1.w + b1.w;
            int oct = sub * 3 + j;
            *(short8*)&As[row * 192 + ((oct ^ (row & 7)) * 8)] = cvt8(o0, o1);
        }
    }
    asm volatile("s_waitcnt vmcnt(0) lgkmcnt(0)" ::: "memory");
    __builtin_amdgcn_sched_barrier(0);
    __builtin_amdgcn_s_barrier();

    short8 af[6];
    {
        int rA = wm + col;
        #pragma unroll
        for (int ks = 0; ks < 6; ks++)
            af[ks] = *(const short8*)&As[rA * 192 + (((ks * 4 + q) ^ (rA & 7)) * 8)];
    }

    for (int ch = 0; ch < 9; ch++) {
        f32x4 acc[2] = {};
        #pragma unroll
        for (int ks = 0; ks < 6; ks++) {
            #pragma unroll
            for (int ni = 0; ni < 2; ni++) {
                int rB = wn + ni * 16 + col;
                short8 bf = *(const short8*)&Ws[rB * 192 + (((ks * 4 + q) ^ (rB & 7)) * 8)];
                acc[ni] = __builtin_amdgcn_mfma_f32_16x16x32_bf16(af[ks], bf, acc[ni], 0, 0, 0);
            }
        }
        asm volatile("s_waitcnt lgkmcnt(0)" ::: "memory");
        __builtin_amdgcn_sched_barrier(0);
        __builtin_amdgcn_s_barrier();
        if (ch < 8) stageW(ch + 1);
        #pragma unroll
        for (int ni = 0; ni < 2; ni++) {
            int n = ch * 64 + wn + ni * 16 + col;
            float bi = bias[n];
            int h18 = n >> 5;
            int sel = h18 / 6;
            int head = h18 - sel * 6;
            #pragma unroll
            for (int r4 = 0; r4 < 4; r4++) {
                int m = m0 + wm + q * 4 + r4;
                float v = acc[ni][r4] + bi;
                size_t idx = ((size_t)head * NPIX + m) * 32 + (n & 31);
                if (sel == 0)      qb[idx] = v * 0.17677669529663687f;
                else if (sel == 1) kb[idx] = __float2bfloat16(v);
                else               vb[idx] = __float2bfloat16(v);
            }
        }
        if (ch < 8) {
            asm volatile("s_waitcnt vmcnt(8)" ::: "memory");
            __builtin_amdgcn_s_barrier();
        }
    }
}

// ---------------- fused tail, 16 waves (unchanged) ----------------
__global__ __launch_bounds__(1024, 4) void tail_fused(
    const __hip_bfloat16* __restrict__ A, const __hip_bfloat16* __restrict__ Wp,
    const float* __restrict__ pb, const float* __restrict__ resid,
    const float* __restrict__ gamma1, const float* __restrict__ ln2w, const float* __restrict__ ln2b,
    const __hip_bfloat16* __restrict__ W1, const float* __restrict__ b1,
    const __hip_bfloat16* __restrict__ W2, const float* __restrict__ b2,
    const float* __restrict__ gamma2, const int* __restrict__ quality,
    float* __restrict__ outf)
{
    __shared__ __hip_bfloat16 arena[64 * 768];     // 96 KB: Ms; top 24 KB doubles as Hs
    __shared__ __hip_bfloat16 Wsb[2][64 * 192];    // 2 x 24 KB
    __shared__ float lnred[4][64][2];              // 2 KB
    __hip_bfloat16* Hs = arena + 36864;            // 24 KB

    int tid = threadIdx.x;
    int wave = tid >> 6, lane = tid & 63;
    int q = lane >> 4, col = lane & 15;
    int wm = (wave >> 2) * 16, wq4 = wave & 3;
    int m0 = blockIdx.x * 64;
    int s = quality[0] - 1;

    stage_rows(A + (size_t)m0 * DIM, (char*)Hs, wave, lane);
    stage_rows(Wp, (char*)&Wsb[0][0], wave, lane);
    stage_rows(Wp + 64 * DIM, (char*)&Wsb[1][0], wave, lane);
    asm volatile("s_waitcnt vmcnt(2)" ::: "memory");
    __builtin_amdgcn_s_barrier();

    short8 afp[6];
    {
        int rA = wm + col;
        #pragma unroll
        for (int ks = 0; ks < 6; ks++)
            afp[ks] = *(const short8*)&Hs[rA * 192 + (((ks * 4 + q) ^ (rA & 7)) * 8)];
    }

    float v[3][4];
    float sm[4] = {}, sq[4] = {};
    auto proj_chunk = [&](int ch, const __hip_bfloat16* wsb) {
        f32x4 pacc = {};
        int rB = wq4 * 16 + col;
        #pragma unroll
        for (int ks = 0; ks < 6; ks++) {
            short8 bf = *(const short8*)&wsb[rB * 192 + (((ks * 4 + q) ^ (rB & 7)) * 8)];
            pacc = __builtin_amdgcn_mfma_f32_16x16x32_bf16(afp[ks], bf, pacc, 0, 0, 0);
        }
        int n = ch * 64 + wq4 * 16 + col;
        float bi = pb[n];
        float g = fabsf(gamma1[s * DIM + n]);
        #pragma unroll
        for (int r = 0; r < 4; r++) {
            int m = m0 + wm + q * 4 + r;
            v[ch][r] = resid[(size_t)m * DIM + n] + g * (pacc[r] + bi);
            sm[r] += v[ch][r]; sq[r] += v[ch][r] * v[ch][r];
        }
    };

    proj_chunk(0, &Wsb[0][0]);
    __builtin_amdgcn_s_barrier();
    stage_rows(Wp + 128 * DIM, (char*)&Wsb[0][0], wave, lane);
    asm volatile("s_waitcnt vmcnt(2)" ::: "memory");
    __builtin_amdgcn_s_barrier();
    proj_chunk(1, &Wsb[1][0]);
    __builtin_amdgcn_s_barrier();
    stage_rows(W1, (char*)&Wsb[1][0], wave, lane);
    asm volatile("s_waitcnt vmcnt(2)" ::: "memory");
    __builtin_amdgcn_s_barrier();
    proj_chunk(2, &Wsb[0][0]);

    #pragma unroll
    for (int off = 1; off <= 8; off <<= 1)
        #pragma unroll
        for (int r = 0; r < 4; r++) {
            sm[r] += __shfl_xor(sm[r], off);
            sq[r] += __shfl_xor(sq[r], off);
        }
    if (col == 0) {
        #pragma unroll
        for (int r = 0; r < 4; r++) {
            lnred[wq4][wm + q * 4 + r][0] = sm[r];
            lnred[wq4][wm + q * 4 + r][1] = sq[r];
        }
    }
    LDS_SYNC();
    float mu[4], rstd[4];
    #pragma unroll
    for (int r = 0; r < 4; r++) {
        int ml = wm + q * 4 + r;
        float smt = lnred[0][ml][0] + lnred[1][ml][0] + lnred[2][ml][0] + lnred[3][ml][0];
        float sqt = lnred[0][ml][1] + lnred[1][ml][1] + lnred[2][ml][1] + lnred[3][ml][1];
        mu[r] = smt * (1.0f / DIM);
        float var = sqt * (1.0f / DIM) - mu[r] * mu[r];
        rstd[r] = rsqrtf(var + 1e-5f);
    }
    #pragma unroll
    for (int ch = 0; ch < 3; ch++) {
        int n = ch * 64 + wq4 * 16 + col;
        float lw = ln2w[n], lb = ln2b[n];
        #pragma unroll
        for (int r = 0; r < 4; r++) {
            int ml = wm + q * 4 + r;
            Hs[ml * 192 + (((n >> 3) ^ (ml & 7)) * 8) + (n & 7)] =
                __float2bfloat16((v[ch][r] - mu[r]) * rstd[r] * lw + lb);
        }
    }
    LDS_SYNC();
    short8 af1[6];
    {
        int rowA = wm + col;
        #pragma unroll
        for (int ks = 0; ks < 6; ks++)
            af1[ks] = *(const short8*)&Hs[rowA * 192 + (((ks * 4 + q) ^ (rowA & 7)) * 8)];
    }
    LDS_SYNC();

    for (int t = 0; t < 12; t++) {
        if (t < 11) stage_rows(W1 + (size_t)(t + 1) * 64 * DIM, (char*)&Wsb[t & 1][0], wave, lane);
        else        stage_w2(W2, 0, (char*)&Wsb[1][0], wave, lane);
        asm volatile("s_waitcnt vmcnt(2)" ::: "memory");
        __builtin_amdgcn_s_barrier();
        const __hip_bfloat16* wsb = &Wsb[(t + 1) & 1][0];
        f32x4 a1 = {};
        int rB = wq4 * 16 + col;
        #pragma unroll
        for (int ks = 0; ks < 6; ks++) {
            short8 bf = *(const short8*)&wsb[rB * 192 + (((ks * 4 + q) ^ (rB & 7)) * 8)];
            a1 = __builtin_amdgcn_mfma_f32_16x16x32_bf16(af1[ks], bf, a1, 0, 0, 0);
        }
        int n = t * 64 + wq4 * 16 + col;
        float bi = b1[n];
        int oct = n >> 3;
        #pragma unroll
        for (int r4 = 0; r4 < 4; r4++) {
            int row = wm + q * 4 + r4;
            float vv = a1[r4] + bi;
            float u = 0.7978845608f * (vv + 0.044715f * vv * vv * vv);
            float tt = 1.f - 2.f / (__expf(2.f * u) + 1.f);
            vv = 0.5f * vv * (1.f + tt);
            int osw = (oct & ~7) | ((oct ^ row) & 7);
            *(__hip_bfloat16*)((char*)arena + row * 1536 + osw * 16 + (n & 7) * 2) =
                __float2bfloat16(vv);
        }
        __builtin_amdgcn_s_barrier();
    }
    LDS_SYNC();

    f32x4 acc2[3] = {};
    for (int ch = 0; ch < 12; ch++) {
        if (ch < 11) {
            stage_w2(W2, ch + 1, (char*)&Wsb[ch & 1][0], wave, lane);
            asm volatile("s_waitcnt vmcnt(2)" ::: "memory");
        } else {
            asm volatile("s_waitcnt vmcnt(0)" ::: "memory");
        }
        __builtin_amdgcn_s_barrier();
        const __hip_bfloat16* wsb = &Wsb[(ch + 1) & 1][0];
        #pragma unroll
        for (int ks = 0; ks < 2; ks++) {
            int row = wm + col;
            int og = ch * 8 + ks * 4 + q;
            int osw = (og & ~7) | ((og ^ row) & 7);
            short8 a2 = *(const short8*)((char*)arena + row * 1536 + osw * 16);
            #pragma unroll
            for (int f = 0; f < 3; f++) {
                int rB = f * 64 + wq4 * 16 + col;
                short8 bf = *(const short8*)&wsb[rB * 64 + (((ks * 4 + q) ^ (rB & 7)) * 8)];
                acc2[f] = __builtin_amdgcn_mfma_f32_16x16x32_bf16(a2, bf, acc2[f], 0, 0, 0);
            }
        }
        __builtin_amdgcn_s_barrier();
    }

    #pragma unroll
    for (int f = 0; f < 3; f++) {
        int n = f * 64 + wq4 * 16 + col;
        float g = fabsf(gamma2[s * DIM + n]);
        float bi = b2[n];
        #pragma unroll
        for (int r4 = 0; r4 < 4; r4++) {
            int m = m0 + wm + q * 4 + r4;
            outf[(size_t)m * DIM + n] = v[f][r4] + g * (acc2[f][r4] + bi);
        }
    }
}

// ---------------- MFMA neighborhood attention (+ piggybacked wp/wf1/wf2 cvt blocks) ----------------
// One block per (8x8 tile, head), 4 waves. Wave w owns queries [w*16, w*16+16).
// QK^T: 13 mfma_16x16x32 (B from Ks[208][40], 2-way banks = free). Mask+rpb on C-frags.
// Softmax: in-register + 4 shfl_xor over col-lanes. P->LDS bf16 (per-wave). PV: 14 MFMAs,
// B from transposed Vt[32][228] (conflict-free b128 reads).
__global__ __launch_bounds__(256, 2) void attn_mfma(
    const float* __restrict__ qbuf, const __hip_bfloat16* __restrict__ kbuf,
    const __hip_bfloat16* __restrict__ vbuf, const float* __restrict__ rpb,
    __hip_bfloat16* __restrict__ out,
    const float* __restrict__ pw, const float* __restrict__ f1w, const float* __restrict__ f2w,
    __hip_bfloat16* __restrict__ dp, __hip_bfloat16* __restrict__ df1, __hip_bfloat16* __restrict__ df2)
{
    if (blockIdx.x >= 256) {
        // weight-cvt blocks, hidden under attention (outputs needed only by tail_fused)
        if (blockIdx.y != 0) return;
        int blk = blockIdx.x - 256, t = threadIdx.x;
        const float* s; __hip_bfloat16* d; int base;
        if (blk < 36)       { s = pw;  d = dp;  base = blk * 1024; }
        else if (blk < 180) { s = f1w; d = df1; base = (blk - 36) * 1024; }
        else                { s = f2w; d = df2; base = (blk - 180) * 1024; }
        int idx = base + t * 4;
        float4 v4 = *(const float4*)(s + idx);
        union { ushort4 u; __hip_bfloat16 h[4]; } o;
        o.h[0] = __float2bfloat16(v4.x); o.h[1] = __float2bfloat16(v4.y);
        o.h[2] = __float2bfloat16(v4.z); o.h[3] = __float2bfloat16(v4.w);
        *(ushort4*)&d[idx] = o.u;
        return;
    }

    __shared__ __hip_bfloat16 Ks[208 * 40];      // [key][40]; rows 196..207 junk (masked)
    __shared__ __hip_bfloat16 Vt[32 * 228];      // [d][key]; keys 196..223 zeroed
    __shared__ __hip_bfloat16 Ps[4][16 * 232];   // per-wave P [q][key]; keys 208..223 zeroed
    __shared__ float rpbs[169];

    int head = blockIdx.y, tile = blockIdx.x;
    int ti0 = (tile >> 4) * 8, tj0 = (tile & 15) * 8;
    int wi0 = ti0 - 3; wi0 = wi0 < 0 ? 0 : (wi0 > IMH - WIN ? IMH - WIN : wi0);
    int wj0 = tj0 - 3; wj0 = wj0 < 0 ? 0 : (wj0 > IMW - WIN ? IMW - WIN : wj0);
    int tid = threadIdx.x;
    const size_t hbase = (size_t)head * NPIX;

    // stage K rows + transposed V
    for (int c = tid; c < 784; c += 256) {
        int i = c / 56, part = c - i * 56;
        int n = i * WIN + (part >> 2);
        int d0 = (part & 3) * 8;
        size_t goff = (hbase + (size_t)(wi0 + i) * IMW + wj0) * 32 + part * 8;
        short8 kk = *(const short8*)(kbuf + goff);
        short8 vv = *(const short8*)(vbuf + goff);
        *(short8*)&Ks[n * 40 + d0] = kk;
        union { short8 v; unsigned short u[8]; } cu; cu.v = vv;
        #pragma unroll
        for (int e = 0; e < 8; e++)
            *(unsigned short*)&Vt[(d0 + e) * 228 + n] = cu.u[e];
    }
    for (int c = tid; c < 896; c += 256) {          // zero Vt pad keys [196,224)
        int d = c / 28, k = 196 + (c - d * 28);
        *(unsigned short*)&Vt[d * 228 + k] = 0;
    }
    if (tid < 169) rpbs[tid] = rpb[head * 169 + tid];

    int w = tid >> 6, l = tid & 63;
    int cl = l & 15, ch = l >> 4;
    #pragma unroll
    for (int j = 0; j < 4; j++)                      // zero Ps pad keys [208,224)
        *(unsigned short*)&Ps[w][cl * 232 + 208 + ch * 4 + j] = 0;

    // Q A-fragment: row = cl (query), k = ch*8+e
    int p0 = w * 16 + cl;
    int qpi = ti0 + (p0 >> 3), qpj = tj0 + (p0 & 7);
    const float4* qp = (const float4*)(qbuf + (hbase + (size_t)(qpi * IMW + qpj)) * 32 + ch * 8);
    short8 afq = cvt8(qp[0], qp[1]);

    // per-r query geometry (C rows = ch*4 + r)
    int pi_r[4], pj_r[4], si_r[4], sj_r[4];
    #pragma unroll
    for (int r = 0; r < 4; r++) {
        int qr = w * 16 + ch * 4 + r;
        int pi = ti0 + (qr >> 3), pj = tj0 + (qr & 7);
        int si = pi - 3; si = si < 0 ? 0 : (si > IMH - KSZ ? IMH - KSZ : si);
        int sj = pj - 3; sj = sj < 0 ? 0 : (sj > IMW - KSZ ? IMW - KSZ : sj);
        pi_r[r] = pi; pj_r[r] = pj; si_r[r] = si; sj_r[r] = sj;
    }

    __syncthreads();

    // QK^T: 13 n-tiles of 16 keys
    f32x4 sc[13] = {};
    #pragma unroll
    for (int t = 0; t < 13; t++) {
        short8 bk = *(const short8*)&Ks[(t * 16 + cl) * 40 + ch * 8];
        sc[t] = __builtin_amdgcn_mfma_f32_16x16x32_bf16(afq, bk, sc[t], 0, 0, 0);
    }

    // mask + rpb bias + row max
    float mrow[4] = {-1e30f, -1e30f, -1e30f, -1e30f};
    #pragma unroll
    for (int t = 0; t < 13; t++) {
        int n = t * 16 + cl;
        int ni = (n * 9363) >> 17;   // n / 14, exact for n < 208
        int nj = n - ni * 14;
        int gi = wi0 + ni, gj = wj0 + nj;
        #pragma unroll
        for (int r = 0; r < 4; r++) {
            int di = gi - si_r[r], dj = gj - sj_r[r];
            bool valid = ((unsigned)di < 7u) && ((unsigned)dj < 7u);
            int bix = (gi - pi_r[r] + 6) * 13 + (gj - pj_r[r] + 6);
            float b = rpbs[valid ? bix : 0];
            float sv = valid ? sc[t][r] + b : -1e30f;
            sc[t][r] = sv;
            mrow[r] = fmaxf(mrow[r], sv);
        }
    }
    #pragma unroll
    for (int off = 1; off <= 8; off <<= 1)
        #pragma unroll
        for (int r = 0; r < 4; r++) mrow[r] = fmaxf(mrow[r], __shfl_xor(mrow[r], off));

    // exp + row sum + P -> LDS (bf16)
    float lrow[4] = {};
    #pragma unroll
    for (int t = 0; t < 13; t++) {
        #pragma unroll
        for (int r = 0; r < 4; r++) {
            float e = __expf(sc[t][r] - mrow[r]);
            lrow[r] += e;
            Ps[w][(ch * 4 + r) * 232 + t * 16 + cl] = __float2bfloat16(e);
        }
    }
    #pragma unroll
    for (int off = 1; off <= 8; off <<= 1)
        #pragma unroll
        for (int r = 0; r < 4; r++) lrow[r] += __shfl_xor(lrow[r], off);

    // PV: P[16x224] @ V[224x32], per-wave (no barrier: Ps wave-local)
    f32x4 o[2] = {};
    #pragma unroll
    for (int ks = 0; ks < 7; ks++) {
        short8 ap = *(const short8*)&Ps[w][cl * 232 + ks * 32 + ch * 8];
        #pragma unroll
        for (int nt = 0; nt < 2; nt++) {
            short8 bv = *(const short8*)&Vt[(nt * 16 + cl) * 228 + ks * 32 + ch * 8];
            o[nt] = __builtin_amdgcn_mfma_f32_16x16x32_bf16(ap, bv, o[nt], 0, 0, 0);
        }
    }

    // epilogue: /l, bf16 store
    #pragma unroll
    for (int r = 0; r < 4; r++) {
        int qr = w * 16 + ch * 4 + r;
        int pi = ti0 + (qr >> 3), pj = tj0 + (qr & 7);
        float rl = 1.f / lrow[r];
        __hip_bfloat16* op = out + (size_t)(pi * IMW + pj) * DIM + head * HD;
        op[cl]      = __float2bfloat16(o[0][r] * rl);
        op[16 + cl] = __float2bfloat16(o[1][r] * rl);
    }
}

extern "C" void kernel_launch(void* const* d_in, const int* in_sizes, int n_in,
                              void* d_out, int out_size, void* d_ws, size_t ws_size,
                              hipStream_t stream)
{
    const float* x      = (const float*)d_in[0];
    const float* qkv_w  = (const float*)d_in[1];
    const float* qkv_b  = (const float*)d_in[2];
    const float* proj_w = (const float*)d_in[3];
    const float* proj_b = (const float*)d_in[4];
    const float* rpb    = (const float*)d_in[5];
    const float* ln1_w  = (const float*)d_in[6];
    const float* ln1_b  = (const float*)d_in[7];
    const float* ln2_w  = (const float*)d_in[8];
    const float* ln2_b  = (const float*)d_in[9];
    const float* fc1_w  = (const float*)d_in[10];
    const float* fc1_b  = (const float*)d_in[11];
    const float* fc2_w  = (const float*)d_in[12];
    const float* fc2_b  = (const float*)d_in[13];
    const float* gamma1 = (const float*)d_in[14];
    const float* gamma2 = (const float*)d_in[15];
    const int*   quality= (const int*)d_in[16];
    float* out = (float*)d_out;

    char* ws = (char*)d_ws;
    float*          qbuf   = (float*)ws;                         // 12.58 MB
    __hip_bfloat16* kbuf   = (__hip_bfloat16*)(ws + 12582912);   // 6.29 MB
    __hip_bfloat16* vbuf   = (__hip_bfloat16*)(ws + 18874368);   // 6.29 MB
    __hip_bfloat16* attn_b = (__hip_bfloat16*)(ws + 44040192);
    __hip_bfloat16* wq     = (__hip_bfloat16*)(ws + 50331648);
    __hip_bfloat16* wp     = (__hip_bfloat16*)(ws + 50552832);
    __hip_bfloat16* wf1    = (__hip_bfloat16*)(ws + 50626560);
    __hip_bfloat16* wf2    = (__hip_bfloat16*)(ws + 50921472);

    // 0. qkv weights->bf16 (108 blocks)
    cvt_w<<<108, 256, 0, stream>>>(qkv_w, wq);
    // 1. QKV GEMM with fused LN1
    qkv_ln_gemm<<<512, 256, 0, stream>>>(
        x, ln1_w, ln1_b, wq, qkv_b, qbuf, kbuf, vbuf);
    // 2. MFMA neighborhood attention (+324 piggyback blocks converting wp/wf1/wf2)
    attn_mfma<<<dim3(256 + 324, NHD), 256, 0, stream>>>(
        qbuf, kbuf, vbuf, rpb, attn_b, proj_w, fc1_w, fc2_w, wp, wf1, wf2);
    // 3. fused tail (16 waves): proj + resid + |g1| + LN2 + FC1 + GELU + FC2 + resid + |g2|
    tail_fused<<<256, 1024, 0, stream>>>(
        attn_b, wp, proj_b, x, gamma1, ln2_w, ln2_b,
        wf1, fc1_b, wf2, fc2_b, gamma2, quality, out);
}

// Round 9
// 163.108 us; speedup vs baseline: 1.0548x; 1.0288x over previous
//
#include <hip/hip_runtime.h>
#include <hip/hip_bf16.h>
#include <math.h>

#define DIM 192
#define NHD 6
#define HD 32
#define KSZ 7
#define HID 768
#define IMH 128
#define IMW 128
#define NPIX (IMH*IMW)
#define WIN 14
#define KPAD 40

typedef __attribute__((ext_vector_type(8))) short short8;
typedef __attribute__((ext_vector_type(4))) float f32x4;

#define LDS_SYNC() do { \
    asm volatile("s_waitcnt lgkmcnt(0)" ::: "memory"); \
    __builtin_amdgcn_sched_barrier(0); \
    __builtin_amdgcn_s_barrier(); } while (0)

// ---------------- qkv weight fp32->bf16 (108 blocks; wp/wf1/wf2 ride in the attn launch) ----------------
__global__ __launch_bounds__(256) void cvt_w(
    const float* __restrict__ qw, __hip_bfloat16* __restrict__ dq)
{
    int idx = blockIdx.x * 1024 + threadIdx.x * 4;
    float4 v4 = *(const float4*)(qw + idx);
    union { ushort4 u; __hip_bfloat16 h[4]; } o;
    o.h[0] = __float2bfloat16(v4.x); o.h[1] = __float2bfloat16(v4.y);
    o.h[2] = __float2bfloat16(v4.z); o.h[3] = __float2bfloat16(v4.w);
    *(ushort4*)&dq[idx] = o.u;
}

__device__ __forceinline__ void gl_lds16(const void* g, void* l) {
    __builtin_amdgcn_global_load_lds(
        (const __attribute__((address_space(1))) void*)g,
        (__attribute__((address_space(3))) void*)l, 16, 0, 0);
}

__device__ __forceinline__ short8 cvt8(float4 a, float4 b) {
    union { short8 v; __hip_bfloat16 h[8]; } u;
    u.h[0] = __float2bfloat16(a.x); u.h[1] = __float2bfloat16(a.y);
    u.h[2] = __float2bfloat16(a.z); u.h[3] = __float2bfloat16(a.w);
    u.h[4] = __float2bfloat16(b.x); u.h[5] = __float2bfloat16(b.y);
    u.h[6] = __float2bfloat16(b.z); u.h[7] = __float2bfloat16(b.w);
    return u.v;
}

// ---- 1024-thread staging: 64 rows x 192 K (1536 slots of 16B), 96 slots/wave
__device__ __forceinline__ void stage_rows(const __hip_bfloat16* __restrict__ src,
                                           char* ldsbase, int wave, int lane) {
    int c0 = wave * 96 + lane;
    int r0 = c0 / 24, k0 = c0 - r0 * 24;
    gl_lds16(src + (size_t)r0 * DIM + ((k0 ^ (r0 & 7)) * 8), ldsbase + (wave * 96) * 16);
    int c1 = wave * 96 + 64 + (lane & 31);
    int r1 = c1 / 24, k1 = c1 - r1 * 24;
    if (lane < 32)
        gl_lds16(src + (size_t)r1 * DIM + ((k1 ^ (r1 & 7)) * 8), ldsbase + (wave * 96 + 64) * 16);
}
__device__ __forceinline__ void stage_w2(const __hip_bfloat16* __restrict__ W2, int ch,
                                         char* ldsbase, int wave, int lane) {
    int i0 = wave * 96 + lane;
    int r0 = i0 >> 3, o0 = i0 & 7;
    gl_lds16(W2 + (size_t)r0 * HID + ch * 64 + ((o0 ^ (r0 & 7)) * 8), ldsbase + (wave * 96) * 16);
    int i1 = wave * 96 + 64 + (lane & 31);
    int r1 = i1 >> 3, o1 = i1 & 7;
    if (lane < 32)
        gl_lds16(W2 + (size_t)r1 * HID + ch * 64 + ((o1 ^ (r1 & 7)) * 8), ldsbase + (wave * 96 + 64) * 16);
}

// ---------------- QKV GEMM with fused LN1 (r6 config; q now written as bf16) ----------------
__global__ __launch_bounds__(256, 4) void qkv_ln_gemm(
    const float* __restrict__ x, const float* __restrict__ lnw, const float* __restrict__ lnb,
    const __hip_bfloat16* __restrict__ W, const float* __restrict__ bias,
    __hip_bfloat16* __restrict__ qb, __hip_bfloat16* __restrict__ kb, __hip_bfloat16* __restrict__ vb)
{
    __shared__ __hip_bfloat16 As[32 * 192];   // 12 KB
    __shared__ __hip_bfloat16 Ws[64 * 192];   // 24 KB (single buffer)
    int tid = threadIdx.x;
    int wave = tid >> 6, lane = tid & 63;
    int q = lane >> 4, col = lane & 15;
    int wm = (wave >> 1) * 16, wn = (wave & 1) * 32;
    int m0 = blockIdx.x * 32;

    auto stageW = [&](int ch) {
        #pragma unroll
        for (int i = 0; i < 6; i++) {
            int c = i * 256 + tid;
            int r = c / 24, kc = c - r * 24;
            gl_lds16(W + (size_t)(ch * 64 + r) * DIM + ((kc ^ (r & 7)) * 8),
                     (char*)&Ws[0] + (i * 256 + wave * 64) * 16);
        }
    };

    stageW(0);

    {
        int row = tid >> 3, sub = tid & 7;
        const float4* xr = (const float4*)(x + (size_t)(m0 + row) * DIM + sub * 24);
        float4 xa[6];
        float s = 0.f;
        #pragma unroll
        for (int i = 0; i < 6; i++) {
            xa[i] = xr[i];
            s += xa[i].x + xa[i].y + xa[i].z + xa[i].w;
        }
        s += __shfl_xor(s, 1); s += __shfl_xor(s, 2); s += __shfl_xor(s, 4);
        float mu = s * (1.0f / DIM);
        float qs = 0.f;
        #pragma unroll
        for (int i = 0; i < 6; i++) {
            float a = xa[i].x - mu, b = xa[i].y - mu, c = xa[i].z - mu, d = xa[i].w - mu;
            qs += a * a + b * b + c * c + d * d;
        }
        qs += __shfl_xor(qs, 1); qs += __shfl_xor(qs, 2); qs += __shfl_xor(qs, 4);
        float rstd = rsqrtf(qs * (1.0f / DIM) + 1e-5f);
        const float4* wv = (const float4*)(lnw + sub * 24);
        const float4* bv = (const float4*)(lnb + sub * 24);
        #pragma unroll
        for (int j = 0; j < 3; j++) {
            float4 v0 = xa[j * 2], v1 = xa[j * 2 + 1];
            float4 w0 = wv[j * 2], w1 = wv[j * 2 + 1];
            float4 b0 = bv[j * 2], b1 = bv[j * 2 + 1];
            float4 o0, o1;
            o0.x = (v0.x - mu) * rstd * w0.x + b0.x;
            o0.y = (v0.y - mu) * rstd * w0.y + b0.y;
            o0.z = (v0.z - mu) * rstd * w0.z + b0.z;
            o0.w = (v0.w - mu) * rstd * w0.w + b0.w;
            o1.x = (v1.x - mu) * rstd * w1.x + b1.x;
            o1.y = (v1.y - mu) * rstd * w1.y + b1.y;
            o1.z = (v1.z - mu) * rstd * w1.z + b1.z;
            o1.w = (v1.w - mu) * rstd * w1.w + b1.w;
            int oct = sub * 3 + j;
            *(short8*)&As[row * 192 + ((oct ^ (row & 7)) * 8)] = cvt8(o0, o1);
        }
    }
    asm volatile("s_waitcnt vmcnt(0) lgkmcnt(0)" ::: "memory");
    __builtin_amdgcn_sched_barrier(0);
    __builtin_amdgcn_s_barrier();

    short8 af[6];
    {
        int rA = wm + col;
        #pragma unroll
        for (int ks = 0; ks < 6; ks++)
            af[ks] = *(const short8*)&As[rA * 192 + (((ks * 4 + q) ^ (rA & 7)) * 8)];
    }

    for (int ch = 0; ch < 9; ch++) {
        f32x4 acc[2] = {};
        #pragma unroll
        for (int ks = 0; ks < 6; ks++) {
            #pragma unroll
            for (int ni = 0; ni < 2; ni++) {
                int rB = wn + ni * 16 + col;
                short8 bf = *(const short8*)&Ws[rB * 192 + (((ks * 4 + q) ^ (rB & 7)) * 8)];
                acc[ni] = __builtin_amdgcn_mfma_f32_16x16x32_bf16(af[ks], bf, acc[ni], 0, 0, 0);
            }
        }
        asm volatile("s_waitcnt lgkmcnt(0)" ::: "memory");
        __builtin_amdgcn_sched_barrier(0);
        __builtin_amdgcn_s_barrier();
        if (ch < 8) stageW(ch + 1);
        #pragma unroll
        for (int ni = 0; ni < 2; ni++) {
            int n = ch * 64 + wn + ni * 16 + col;
            float bi = bias[n];
            int h18 = n >> 5;
            int sel = h18 / 6;
            int head = h18 - sel * 6;
            #pragma unroll
            for (int r4 = 0; r4 < 4; r4++) {
                int m = m0 + wm + q * 4 + r4;
                float v = acc[ni][r4] + bi;
                size_t idx = ((size_t)head * NPIX + m) * 32 + (n & 31);
                if (sel == 0)      qb[idx] = __float2bfloat16(v * 0.17677669529663687f);
                else if (sel == 1) kb[idx] = __float2bfloat16(v);
                else               vb[idx] = __float2bfloat16(v);
            }
        }
        if (ch < 8) {
            asm volatile("s_waitcnt vmcnt(8)" ::: "memory");
            __builtin_amdgcn_s_barrier();
        }
    }
}

// ---------------- fused tail, 16 waves (unchanged) ----------------
__global__ __launch_bounds__(1024, 4) void tail_fused(
    const __hip_bfloat16* __restrict__ A, const __hip_bfloat16* __restrict__ Wp,
    const float* __restrict__ pb, const float* __restrict__ resid,
    const float* __restrict__ gamma1, const float* __restrict__ ln2w, const float* __restrict__ ln2b,
    const __hip_bfloat16* __restrict__ W1, const float* __restrict__ b1,
    const __hip_bfloat16* __restrict__ W2, const float* __restrict__ b2,
    const float* __restrict__ gamma2, const int* __restrict__ quality,
    float* __restrict__ outf)
{
    __shared__ __hip_bfloat16 arena[64 * 768];     // 96 KB: Ms; top 24 KB doubles as Hs
    __shared__ __hip_bfloat16 Wsb[2][64 * 192];    // 2 x 24 KB
    __shared__ float lnred[4][64][2];              // 2 KB
    __hip_bfloat16* Hs = arena + 36864;            // 24 KB

    int tid = threadIdx.x;
    int wave = tid >> 6, lane = tid & 63;
    int q = lane >> 4, col = lane & 15;
    int wm = (wave >> 2) * 16, wq4 = wave & 3;
    int m0 = blockIdx.x * 64;
    int s = quality[0] - 1;

    stage_rows(A + (size_t)m0 * DIM, (char*)Hs, wave, lane);
    stage_rows(Wp, (char*)&Wsb[0][0], wave, lane);
    stage_rows(Wp + 64 * DIM, (char*)&Wsb[1][0], wave, lane);
    asm volatile("s_waitcnt vmcnt(2)" ::: "memory");
    __builtin_amdgcn_s_barrier();

    short8 afp[6];
    {
        int rA = wm + col;
        #pragma unroll
        for (int ks = 0; ks < 6; ks++)
            afp[ks] = *(const short8*)&Hs[rA * 192 + (((ks * 4 + q) ^ (rA & 7)) * 8)];
    }

    float v[3][4];
    float sm[4] = {}, sq[4] = {};
    auto proj_chunk = [&](int ch, const __hip_bfloat16* wsb) {
        f32x4 pacc = {};
        int rB = wq4 * 16 + col;
        #pragma unroll
        for (int ks = 0; ks < 6; ks++) {
            short8 bf = *(const short8*)&wsb[rB * 192 + (((ks * 4 + q) ^ (rB & 7)) * 8)];
            pacc = __builtin_amdgcn_mfma_f32_16x16x32_bf16(afp[ks], bf, pacc, 0, 0, 0);
        }
        int n = ch * 64 + wq4 * 16 + col;
        float bi = pb[n];
        float g = fabsf(gamma1[s * DIM + n]);
        #pragma unroll
        for (int r = 0; r < 4; r++) {
            int m = m0 + wm + q * 4 + r;
            v[ch][r] = resid[(size_t)m * DIM + n] + g * (pacc[r] + bi);
            sm[r] += v[ch][r]; sq[r] += v[ch][r] * v[ch][r];
        }
    };

    proj_chunk(0, &Wsb[0][0]);
    __builtin_amdgcn_s_barrier();
    stage_rows(Wp + 128 * DIM, (char*)&Wsb[0][0], wave, lane);
    asm volatile("s_waitcnt vmcnt(2)" ::: "memory");
    __builtin_amdgcn_s_barrier();
    proj_chunk(1, &Wsb[1][0]);
    __builtin_amdgcn_s_barrier();
    stage_rows(W1, (char*)&Wsb[1][0], wave, lane);
    asm volatile("s_waitcnt vmcnt(2)" ::: "memory");
    __builtin_amdgcn_s_barrier();
    proj_chunk(2, &Wsb[0][0]);

    #pragma unroll
    for (int off = 1; off <= 8; off <<= 1)
        #pragma unroll
        for (int r = 0; r < 4; r++) {
            sm[r] += __shfl_xor(sm[r], off);
            sq[r] += __shfl_xor(sq[r], off);
        }
    if (col == 0) {
        #pragma unroll
        for (int r = 0; r < 4; r++) {
            lnred[wq4][wm + q * 4 + r][0] = sm[r];
            lnred[wq4][wm + q * 4 + r][1] = sq[r];
        }
    }
    LDS_SYNC();
    float mu[4], rstd[4];
    #pragma unroll
    for (int r = 0; r < 4; r++) {
        int ml = wm + q * 4 + r;
        float smt = lnred[0][ml][0] + lnred[1][ml][0] + lnred[2][ml][0] + lnred[3][ml][0];
        float sqt = lnred[0][ml][1] + lnred[1][ml][1] + lnred[2][ml][1] + lnred[3][ml][1];
        mu[r] = smt * (1.0f / DIM);
        float var = sqt * (1.0f / DIM) - mu[r] * mu[r];
        rstd[r] = rsqrtf(var + 1e-5f);
    }
    #pragma unroll
    for (int ch = 0; ch < 3; ch++) {
        int n = ch * 64 + wq4 * 16 + col;
        float lw = ln2w[n], lb = ln2b[n];
        #pragma unroll
        for (int r = 0; r < 4; r++) {
            int ml = wm + q * 4 + r;
            Hs[ml * 192 + (((n >> 3) ^ (ml & 7)) * 8) + (n & 7)] =
                __float2bfloat16((v[ch][r] - mu[r]) * rstd[r] * lw + lb);
        }
    }
    LDS_SYNC();
    short8 af1[6];
    {
        int rowA = wm + col;
        #pragma unroll
        for (int ks = 0; ks < 6; ks++)
            af1[ks] = *(const short8*)&Hs[rowA * 192 + (((ks * 4 + q) ^ (rowA & 7)) * 8)];
    }
    LDS_SYNC();

    for (int t = 0; t < 12; t++) {
        if (t < 11) stage_rows(W1 + (size_t)(t + 1) * 64 * DIM, (char*)&Wsb[t & 1][0], wave, lane);
        else        stage_w2(W2, 0, (char*)&Wsb[1][0], wave, lane);
        asm volatile("s_waitcnt vmcnt(2)" ::: "memory");
        __builtin_amdgcn_s_barrier();
        const __hip_bfloat16* wsb = &Wsb[(t + 1) & 1][0];
        f32x4 a1 = {};
        int rB = wq4 * 16 + col;
        #pragma unroll
        for (int ks = 0; ks < 6; ks++) {
            short8 bf = *(const short8*)&wsb[rB * 192 + (((ks * 4 + q) ^ (rB & 7)) * 8)];
            a1 = __builtin_amdgcn_mfma_f32_16x16x32_bf16(af1[ks], bf, a1, 0, 0, 0);
        }
        int n = t * 64 + wq4 * 16 + col;
        float bi = b1[n];
        int oct = n >> 3;
        #pragma unroll
        for (int r4 = 0; r4 < 4; r4++) {
            int row = wm + q * 4 + r4;
            float vv = a1[r4] + bi;
            float u = 0.7978845608f * (vv + 0.044715f * vv * vv * vv);
            float tt = 1.f - 2.f / (__expf(2.f * u) + 1.f);
            vv = 0.5f * vv * (1.f + tt);
            int osw = (oct & ~7) | ((oct ^ row) & 7);
            *(__hip_bfloat16*)((char*)arena + row * 1536 + osw * 16 + (n & 7) * 2) =
                __float2bfloat16(vv);
        }
        __builtin_amdgcn_s_barrier();
    }
    LDS_SYNC();

    f32x4 acc2[3] = {};
    for (int ch = 0; ch < 12; ch++) {
        if (ch < 11) {
            stage_w2(W2, ch + 1, (char*)&Wsb[ch & 1][0], wave, lane);
            asm volatile("s_waitcnt vmcnt(2)" ::: "memory");
        } else {
            asm volatile("s_waitcnt vmcnt(0)" ::: "memory");
        }
        __builtin_amdgcn_s_barrier();
        const __hip_bfloat16* wsb = &Wsb[(ch + 1) & 1][0];
        #pragma unroll
        for (int ks = 0; ks < 2; ks++) {
            int row = wm + col;
            int og = ch * 8 + ks * 4 + q;
            int osw = (og & ~7) | ((og ^ row) & 7);
            short8 a2 = *(const short8*)((char*)arena + row * 1536 + osw * 16);
            #pragma unroll
            for (int f = 0; f < 3; f++) {
                int rB = f * 64 + wq4 * 16 + col;
                short8 bf = *(const short8*)&wsb[rB * 64 + (((ks * 4 + q) ^ (rB & 7)) * 8)];
                acc2[f] = __builtin_amdgcn_mfma_f32_16x16x32_bf16(a2, bf, acc2[f], 0, 0, 0);
            }
        }
        __builtin_amdgcn_s_barrier();
    }

    #pragma unroll
    for (int f = 0; f < 3; f++) {
        int n = f * 64 + wq4 * 16 + col;
        float g = fabsf(gamma2[s * DIM + n]);
        float bi = b2[n];
        #pragma unroll
        for (int r4 = 0; r4 < 4; r4++) {
            int m = m0 + wm + q * 4 + r4;
            outf[(size_t)m * DIM + n] = v[f][r4] + g * (acc2[f][r4] + bi);
        }
    }
}

// ---------------- MFMA neighborhood attention, 3 blocks/CU (chunked Ps) ----------------
// One block per (8x8 tile, head), 4 waves. QK^T 13 MFMAs; softmax in-register; PV in two
// key-chunks through per-wave Ps[16][136] (LDS 48.2 KB total -> 3 blocks/CU, 2 CU-rounds).
__global__ __launch_bounds__(256, 3) void attn_mfma(
    const __hip_bfloat16* __restrict__ qbuf, const __hip_bfloat16* __restrict__ kbuf,
    const __hip_bfloat16* __restrict__ vbuf, const float* __restrict__ rpb,
    __hip_bfloat16* __restrict__ out,
    const float* __restrict__ pw, const float* __restrict__ f1w, const float* __restrict__ f2w,
    __hip_bfloat16* __restrict__ dp, __hip_bfloat16* __restrict__ df1, __hip_bfloat16* __restrict__ df2)
{
    if (blockIdx.x >= 256) {
        if (blockIdx.y != 0) return;
        int blk = blockIdx.x - 256, t = threadIdx.x;
        const float* s; __hip_bfloat16* d; int base;
        if (blk < 36)       { s = pw;  d = dp;  base = blk * 1024; }
        else if (blk < 180) { s = f1w; d = df1; base = (blk - 36) * 1024; }
        else                { s = f2w; d = df2; base = (blk - 180) * 1024; }
        int idx = base + t * 4;
        float4 v4 = *(const float4*)(s + idx);
        union { ushort4 u; __hip_bfloat16 h[4]; } o;
        o.h[0] = __float2bfloat16(v4.x); o.h[1] = __float2bfloat16(v4.y);
        o.h[2] = __float2bfloat16(v4.z); o.h[3] = __float2bfloat16(v4.w);
        *(ushort4*)&d[idx] = o.u;
        return;
    }

    __shared__ __hip_bfloat16 Ks[208 * 40];      // 16.6 KB; rows 196..207 junk (masked)
    __shared__ __hip_bfloat16 Vt[32 * 228];      // 14.6 KB; keys 196..223 zeroed
    __shared__ __hip_bfloat16 Ps[4][16 * 136];   // 17.4 KB per-wave P chunk buffer
    __shared__ float rpbs[169];

    int head = blockIdx.y, tile = blockIdx.x;
    int ti0 = (tile >> 4) * 8, tj0 = (tile & 15) * 8;
    int wi0 = ti0 - 3; wi0 = wi0 < 0 ? 0 : (wi0 > IMH - WIN ? IMH - WIN : wi0);
    int wj0 = tj0 - 3; wj0 = wj0 < 0 ? 0 : (wj0 > IMW - WIN ? IMW - WIN : wj0);
    int tid = threadIdx.x;
    const size_t hbase = (size_t)head * NPIX;

    for (int c = tid; c < 784; c += 256) {
        int i = c / 56, part = c - i * 56;
        int n = i * WIN + (part >> 2);
        int d0 = (part & 3) * 8;
        size_t goff = (hbase + (size_t)(wi0 + i) * IMW + wj0) * 32 + part * 8;
        short8 kk = *(const short8*)(kbuf + goff);
        short8 vv = *(const short8*)(vbuf + goff);
        *(short8*)&Ks[n * 40 + d0] = kk;
        union { short8 v; unsigned short u[8]; } cu; cu.v = vv;
        #pragma unroll
        for (int e = 0; e < 8; e++)
            *(unsigned short*)&Vt[(d0 + e) * 228 + n] = cu.u[e];
    }
    for (int c = tid; c < 896; c += 256) {          // zero Vt pad keys [196,224)
        int d = c / 28, k = 196 + (c - d * 28);
        *(unsigned short*)&Vt[d * 228 + k] = 0;
    }
    if (tid < 169) rpbs[tid] = rpb[head * 169 + tid];

    int w = tid >> 6, l = tid & 63;
    int cl = l & 15, ch = l >> 4;

    // Q A-fragment (bf16 direct)
    int p0 = w * 16 + cl;
    int qpi = ti0 + (p0 >> 3), qpj = tj0 + (p0 & 7);
    short8 afq = *(const short8*)(qbuf + (hbase + (size_t)(qpi * IMW + qpj)) * 32 + ch * 8);

    int pi_r[4], pj_r[4], si_r[4], sj_r[4];
    #pragma unroll
    for (int r = 0; r < 4; r++) {
        int qr = w * 16 + ch * 4 + r;
        int pi = ti0 + (qr >> 3), pj = tj0 + (qr & 7);
        int si = pi - 3; si = si < 0 ? 0 : (si > IMH - KSZ ? IMH - KSZ : si);
        int sj = pj - 3; sj = sj < 0 ? 0 : (sj > IMW - KSZ ? IMW - KSZ : sj);
        pi_r[r] = pi; pj_r[r] = pj; si_r[r] = si; sj_r[r] = sj;
    }

    __syncthreads();

    // QK^T: 13 n-tiles of 16 keys
    f32x4 sc[13] = {};
    #pragma unroll
    for (int t = 0; t < 13; t++) {
        short8 bk = *(const short8*)&Ks[(t * 16 + cl) * 40 + ch * 8];
        sc[t] = __builtin_amdgcn_mfma_f32_16x16x32_bf16(afq, bk, sc[t], 0, 0, 0);
    }

    // mask + rpb bias + row max
    float mrow[4] = {-1e30f, -1e30f, -1e30f, -1e30f};
    #pragma unroll
    for (int t = 0; t < 13; t++) {
        int n = t * 16 + cl;
        int ni = (n * 9363) >> 17;   // n / 14, exact for n < 208
        int nj = n - ni * 14;
        int gi = wi0 + ni, gj = wj0 + nj;
        #pragma unroll
        for (int r = 0; r < 4; r++) {
            int di = gi - si_r[r], dj = gj - sj_r[r];
            bool valid = ((unsigned)di < 7u) && ((unsigned)dj < 7u);
            int bix = (gi - pi_r[r] + 6) * 13 + (gj - pj_r[r] + 6);
            float b = rpbs[valid ? bix : 0];
            float sv = valid ? sc[t][r] + b : -1e30f;
            sc[t][r] = sv;
            mrow[r] = fmaxf(mrow[r], sv);
        }
    }
    #pragma unroll
    for (int off = 1; off <= 8; off <<= 1)
        #pragma unroll
        for (int r = 0; r < 4; r++) mrow[r] = fmaxf(mrow[r], __shfl_xor(mrow[r], off));

    // exp (all 13 tiles in regs) + row sum
    float lrow[4] = {};
    #pragma unroll
    for (int t = 0; t < 13; t++) {
        #pragma unroll
        for (int r = 0; r < 4; r++) {
            float e = __expf(sc[t][r] - mrow[r]);
            sc[t][r] = e;
            lrow[r] += e;
        }
    }
    #pragma unroll
    for (int off = 1; off <= 8; off <<= 1)
        #pragma unroll
        for (int r = 0; r < 4; r++) lrow[r] += __shfl_xor(lrow[r], off);

    // PV chunk A: keys 0..127 (tiles 0..7, ks 0..3)
    f32x4 o[2] = {};
    #pragma unroll
    for (int t = 0; t < 8; t++)
        #pragma unroll
        for (int r = 0; r < 4; r++)
            Ps[w][(ch * 4 + r) * 136 + t * 16 + cl] = __float2bfloat16(sc[t][r]);
    #pragma unroll
    for (int ks = 0; ks < 4; ks++) {
        short8 ap = *(const short8*)&Ps[w][cl * 136 + ks * 32 + ch * 8];
        #pragma unroll
        for (int nt = 0; nt < 2; nt++) {
            short8 bv = *(const short8*)&Vt[(nt * 16 + cl) * 228 + ks * 32 + ch * 8];
            o[nt] = __builtin_amdgcn_mfma_f32_16x16x32_bf16(ap, bv, o[nt], 0, 0, 0);
        }
    }
    // PV chunk B: keys 128..223 (tiles 8..12 -> cols 0..79; cols 80..95 zeroed)
    #pragma unroll
    for (int t = 8; t < 13; t++)
        #pragma unroll
        for (int r = 0; r < 4; r++)
            Ps[w][(ch * 4 + r) * 136 + (t - 8) * 16 + cl] = __float2bfloat16(sc[t][r]);
    #pragma unroll
    for (int r = 0; r < 4; r++)
        *(unsigned short*)&Ps[w][(ch * 4 + r) * 136 + 80 + cl] = 0;
    #pragma unroll
    for (int ks = 0; ks < 3; ks++) {
        short8 ap = *(const short8*)&Ps[w][cl * 136 + ks * 32 + ch * 8];
        #pragma unroll
        for (int nt = 0; nt < 2; nt++) {
            short8 bv = *(const short8*)&Vt[(nt * 16 + cl) * 228 + (4 + ks) * 32 + ch * 8];
            o[nt] = __builtin_amdgcn_mfma_f32_16x16x32_bf16(ap, bv, o[nt], 0, 0, 0);
        }
    }

    // epilogue: /l, bf16 store
    #pragma unroll
    for (int r = 0; r < 4; r++) {
        int qr = w * 16 + ch * 4 + r;
        int pi = ti0 + (qr >> 3), pj = tj0 + (qr & 7);
        float rl = 1.f / lrow[r];
        __hip_bfloat16* op = out + (size_t)(pi * IMW + pj) * DIM + head * HD;
        op[cl]      = __float2bfloat16(o[0][r] * rl);
        op[16 + cl] = __float2bfloat16(o[1][r] * rl);
    }
}

extern "C" void kernel_launch(void* const* d_in, const int* in_sizes, int n_in,
                              void* d_out, int out_size, void* d_ws, size_t ws_size,
                              hipStream_t stream)
{
    const float* x      = (const float*)d_in[0];
    const float* qkv_w  = (const float*)d_in[1];
    const float* qkv_b  = (const float*)d_in[2];
    const float* proj_w = (const float*)d_in[3];
    const float* proj_b = (const float*)d_in[4];
    const float* rpb    = (const float*)d_in[5];
    const float* ln1_w  = (const float*)d_in[6];
    const float* ln1_b  = (const float*)d_in[7];
    const float* ln2_w  = (const float*)d_in[8];
    const float* ln2_b  = (const float*)d_in[9];
    const float* fc1_w  = (const float*)d_in[10];
    const float* fc1_b  = (const float*)d_in[11];
    const float* fc2_w  = (const float*)d_in[12];
    const float* fc2_b  = (const float*)d_in[13];
    const float* gamma1 = (const float*)d_in[14];
    const float* gamma2 = (const float*)d_in[15];
    const int*   quality= (const int*)d_in[16];
    float* out = (float*)d_out;

    char* ws = (char*)d_ws;
    __hip_bfloat16* qbuf   = (__hip_bfloat16*)ws;                // 6.29 MB (bf16 now)
    __hip_bfloat16* kbuf   = (__hip_bfloat16*)(ws + 12582912);   // 6.29 MB
    __hip_bfloat16* vbuf   = (__hip_bfloat16*)(ws + 18874368);   // 6.29 MB
    __hip_bfloat16* attn_b = (__hip_bfloat16*)(ws + 44040192);
    __hip_bfloat16* wq     = (__hip_bfloat16*)(ws + 50331648);
    __hip_bfloat16* wp     = (__hip_bfloat16*)(ws + 50552832);
    __hip_bfloat16* wf1    = (__hip_bfloat16*)(ws + 50626560);
    __hip_bfloat16* wf2    = (__hip_bfloat16*)(ws + 50921472);

    // 0. qkv weights->bf16 (108 blocks)
    cvt_w<<<108, 256, 0, stream>>>(qkv_w, wq);
    // 1. QKV GEMM with fused LN1 (q written as bf16)
    qkv_ln_gemm<<<512, 256, 0, stream>>>(
        x, ln1_w, ln1_b, wq, qkv_b, qbuf, kbuf, vbuf);
    // 2. MFMA neighborhood attention, 3 blocks/CU (+324 piggyback cvt blocks)
    attn_mfma<<<dim3(256 + 324, NHD), 256, 0, stream>>>(
        qbuf, kbuf, vbuf, rpb, attn_b, proj_w, fc1_w, fc2_w, wp, wf1, wf2);
    // 3. fused tail (16 waves): proj + resid + |g1| + LN2 + FC1 + GELU + FC2 + resid + |g2|
    tail_fused<<<256, 1024, 0, stream>>>(
        attn_b, wp, proj_b, x, gamma1, ln2_w, ln2_b,
        wf1, fc1_b, wf2, fc2_b, gamma2, quality, out);
}